// Round 16
// baseline (94.931 us; speedup 1.0000x reference)
//
#include <hip/hip_runtime.h>

// URGCN layer, MI355X — round 16.
// r15 post-mortem: atomics are THROUGHPUT-bound at the device-scope
// (memory-side, cross-XCD-coherent) atomic point (~15 G with-return ops/s);
// hiding their latency under the GEMM gained nothing. Fix: per-XCD counter
// and bucket partitions + WORKGROUP-scope atomics -> RMW executes in the
// issuing XCD's own L2 (no cross-XCD coherence needed since each counter is
// touched by exactly one XCD; kernel-boundary flush publishes results).
// gather: one node/wave, one coalesced 256B sub-bucket row, ballot/popc
// compaction into LDS (kills the divergent-shfl hazard class entirely).
//
// Algebra: msg_agg = (Σ_e T[src] + u[rel]) / deg, T = h@Wn (bf16 MFMA),
//          u = rel@Wn.  out = Sp + msg_agg, Sp = h@(I+Wself) (f32, in d_out).

constexpr int NNODES = 50000;
constexpr int NEDGES = 600000;
constexpr int NRELS  = 500;
constexpr int DIM    = 128;
constexpr int NXCD   = 8;       // XCDs on MI355X (m09)
constexpr int SCAP   = 8;       // slots per (node, xcd); Poisson(1.5) tail ~3e-5
constexpr int SLOTS  = NXCD * SCAP;   // 64 slots per node
constexpr int OCAP   = 8192;    // overflow list capacity

constexpr int NODE_BLKS = (NNODES + 63) / 64;   // 782
constexpr int REL_BLKS  = (NRELS  + 63) / 64;   // 8
constexpr int TS_BLKS   = NODE_BLKS + REL_BLKS; // 790

constexpr int BP = 136;   // LDS B row pitch (shorts)
constexpr int TP = 136;   // LDS T tile pitch (shorts)
constexpr int SP = 132;   // LDS S tile pitch (floats)

// prep geometry: zero cnt[8*50000] + ocount -> 100016 int4
constexpr int WCONV_BLKS = (DIM * DIM + 255) / 256;            // 64
constexpr int ZERO_INT4S = 100016;
constexpr int ZERO_BLKS  = (ZERO_INT4S + 255) / 256;           // 391
constexpr int PREP_BLKS  = WCONV_BLKS + ZERO_BLKS;             // 455

// fill geometry: 4 edges/thread over the first FILL_BLKS blocks of fillts
constexpr int FILL_THREADS = NEDGES / 4;                       // 150000
constexpr int FILL_BLKS    = (FILL_THREADS + 255) / 256;       // 586

// gather geometry: 1 node per wave
constexpr int GATHER_BLKS  = (NNODES * 64 + 255) / 256;        // 12500

// ---------------- workspace layout (bytes), ~27.5 MB ----------------
constexpr size_t OFF_CNT_B  = 0;          // int[8][50000] per-XCD counters (1.6MB)
constexpr size_t OFF_OCNT_B = 1600000;    // int ocount (zeroed with cnt)
constexpr size_t OFF_OBUF_B = 1600256;    // uint2[8192]
constexpr size_t OFF_SBK_B  = 1665792;    // uint[50000][8][8] sub-buckets (12.8MB)
constexpr size_t OFF_BTN_B  = 14465792;   // ushort[128*128] Wn^T bf16
constexpr size_t OFF_BTS_B  = 14498560;   // ushort[128*128] (I+Ws)^T bf16
constexpr size_t OFF_T_B    = 14531328;   // ushort[50000*128]
constexpr size_t OFF_U_B    = 27331328;   // ushort[500*128]

typedef short s8f __attribute__((ext_vector_type(8)));   // 8 bf16
typedef float f4  __attribute__((ext_vector_type(4)));   // MFMA acc

static __device__ __forceinline__ unsigned short f2bf(float f) {
    unsigned u = __builtin_bit_cast(unsigned, f);
    u += 0x7FFFu + ((u >> 16) & 1u);
    return (unsigned short)(u >> 16);
}
static __device__ __forceinline__ float bflo(unsigned v) {
    return __builtin_bit_cast(float, v << 16);
}
static __device__ __forceinline__ float bfhi(unsigned v) {
    return __builtin_bit_cast(float, v & 0xFFFF0000u);
}
static __device__ __forceinline__ unsigned xcc_id() {
    unsigned x;
    asm volatile("s_getreg_b32 %0, hwreg(HW_REG_XCC_ID)" : "=s"(x));
    return x & (NXCD - 1);   // mask: OOB protection only
}

// ---------------------------------------------------------------------------
__global__ __launch_bounds__(256) void prep(const float* __restrict__ wn,
                                            const float* __restrict__ wsf,
                                            unsigned short* __restrict__ btn,
                                            unsigned short* __restrict__ bts,
                                            int4* __restrict__ cnt4)
{
    int b = blockIdx.x;
    if (b < WCONV_BLKS) {
        int idx = b * 256 + threadIdx.x;
        int k = idx >> 7, j = idx & 127;
        btn[(size_t)j * DIM + k] = f2bf(wn[idx]);                         // Wn^T
        bts[(size_t)j * DIM + k] = f2bf(wsf[idx] + (k == j ? 1.f : 0.f)); // (I+Ws)^T
    } else {
        int idx = (b - WCONV_BLKS) * 256 + threadIdx.x;
        if (idx < ZERO_INT4S) cnt4[idx] = make_int4(0, 0, 0, 0);
    }
}

// ---------------------------------------------------------------------------
// fillts: fused. Blocks [0,586) own 4 edges/thread:
//   START: load edges, issue 4 L2-LOCAL with-return atomics (per-XCD shard)
//   MIDDLE: the full two-phase GEMM (T/U then Sp)
//   END: consume returned slots -> sub-bucket stores (L2-resident region)
// ---------------------------------------------------------------------------
__global__ __launch_bounds__(256, 4) void fillts(
    const int* __restrict__ edges,
    int* __restrict__ cnt, unsigned* __restrict__ sbuck,
    int* __restrict__ ocount, uint2* __restrict__ obuf,
    const float* __restrict__ nodes, const float* __restrict__ rels,
    const unsigned short* __restrict__ btn, const unsigned short* __restrict__ bts,
    unsigned short* __restrict__ T, unsigned short* __restrict__ U,
    float* __restrict__ Sp)
{
    __shared__ __align__(16) char ldsRaw[DIM * BP * 2];   // 34816 B
    unsigned short* ldsB = (unsigned short*)ldsRaw;
    unsigned short* ldsT = (unsigned short*)ldsRaw;
    float*          ldsS = (float*)ldsRaw;

    int blk = blockIdx.x;
    int t   = threadIdx.x;

    // ---- fill issue phase: L2-local atomics on this XCD's counter shard ----
    bool doFill = false;
    int d0 = 0, d1 = 0, d2 = 0, d3 = 0;
    unsigned p0 = 0, p1 = 0, p2 = 0, p3 = 0;
    int q0 = 0, q1 = 0, q2 = 0, q3 = 0;
    unsigned xcd = 0;
    if (blk < FILL_BLKS) {
        int t4 = blk * 256 + t;
        if (t4 < FILL_THREADS) {
            doFill = true;
            xcd = xcc_id();
            int* mycnt = cnt + (size_t)xcd * NNODES;
            const int4* ei = (const int4*)edges + (size_t)t4 * 3;
            int4 a = ei[0];
            int4 b = ei[1];
            int4 cc = ei[2];
            // [s0 r0 d0 s1][r1 d1 s2 r2][d2 s3 r3 d3]
            d0 = a.z;  d1 = b.y;  d2 = cc.x; d3 = cc.w;
            p0 = (unsigned)a.x  | ((unsigned)a.y  << 16);
            p1 = (unsigned)a.w  | ((unsigned)b.x  << 16);
            p2 = (unsigned)b.z  | ((unsigned)b.w  << 16);
            p3 = (unsigned)cc.y | ((unsigned)cc.z << 16);
            // WORKGROUP scope -> no sc1 -> RMW executes in this XCD's L2.
            // Correct because only this XCD's blocks touch this shard.
            q0 = __hip_atomic_fetch_add(mycnt + d0, 1, __ATOMIC_RELAXED, __HIP_MEMORY_SCOPE_WORKGROUP);
            q1 = __hip_atomic_fetch_add(mycnt + d1, 1, __ATOMIC_RELAXED, __HIP_MEMORY_SCOPE_WORKGROUP);
            q2 = __hip_atomic_fetch_add(mycnt + d2, 1, __ATOMIC_RELAXED, __HIP_MEMORY_SCOPE_WORKGROUP);
            q3 = __hip_atomic_fetch_add(mycnt + d3, 1, __ATOMIC_RELAXED, __HIP_MEMORY_SCOPE_WORKGROUP);
        }
    }

    // ---- GEMM ----
    bool isRel = blk >= NODE_BLKS;
    const float* A = isRel ? rels : nodes;
    int nrows = isRel ? NRELS : NNODES;
    int rowbase = (isRel ? (blk - NODE_BLKS) : blk) * 64;

    int wv = t >> 6;
    int l  = t & 63;
    int r0 = rowbase + wv * 16;
    int m  = l & 15;
    int kg = l >> 4;
    int arow  = r0 + m;
    int arowc = arow < nrows ? arow : nrows - 1;

    s8f afrag[4];
    #pragma unroll
    for (int ks = 0; ks < 4; ++ks) {
        const float* p = A + (size_t)arowc * DIM + ks * 32 + kg * 8;
        float4 x = *(const float4*)p;
        float4 y = *(const float4*)(p + 4);
        s8f a;
        a[0] = (short)f2bf(x.x); a[1] = (short)f2bf(x.y);
        a[2] = (short)f2bf(x.z); a[3] = (short)f2bf(x.w);
        a[4] = (short)f2bf(y.x); a[5] = (short)f2bf(y.y);
        a[6] = (short)f2bf(y.z); a[7] = (short)f2bf(y.w);
        afrag[ks] = a;
    }

    // phase 1: T/U = A @ Wn
    #pragma unroll
    for (int i = 0; i < 8; ++i) {
        int idx = t + i * 256;
        int col = idx >> 4, slot = idx & 15;
        *(uint4*)(ldsB + (size_t)col * BP + slot * 8) =
            *(const uint4*)(btn + (size_t)col * DIM + slot * 8);
    }
    __syncthreads();

    f4 acc[8];
    #pragma unroll
    for (int ct = 0; ct < 8; ++ct) {
        int col = ct * 16 + m;
        const unsigned short* bp = ldsB + (size_t)col * BP + kg * 8;
        f4 a = {0.f, 0.f, 0.f, 0.f};
        #pragma unroll
        for (int ks = 0; ks < 4; ++ks)
            a = __builtin_amdgcn_mfma_f32_16x16x32_bf16(afrag[ks], *(const s8f*)(bp + ks * 32), a, 0, 0, 0);
        acc[ct] = a;
    }
    __syncthreads();

    #pragma unroll
    for (int ct = 0; ct < 8; ++ct)
        #pragma unroll
        for (int r = 0; r < 4; ++r)
            ldsT[((size_t)wv * 16 + kg * 4 + r) * TP + ct * 16 + m] = f2bf(acc[ct][r]);
    __syncthreads();

    unsigned short* Tout = isRel ? U : T;
    #pragma unroll
    for (int p = 0; p < 4; ++p) {
        int row = p * 4 + kg;
        int rg  = r0 + row;
        if (rg < nrows)
            *(uint4*)(Tout + (size_t)rg * DIM + m * 8) =
                *(const uint4*)&ldsT[((size_t)wv * 16 + row) * TP + m * 8];
    }

    if (!isRel) {
        __syncthreads();
        // phase 2: Sp = A @ (I+Ws)
        #pragma unroll
        for (int i = 0; i < 8; ++i) {
            int idx = t + i * 256;
            int col = idx >> 4, slot = idx & 15;
            *(uint4*)(ldsB + (size_t)col * BP + slot * 8) =
                *(const uint4*)(bts + (size_t)col * DIM + slot * 8);
        }
        __syncthreads();

        #pragma unroll
        for (int ct = 0; ct < 8; ++ct) {
            int col = ct * 16 + m;
            const unsigned short* bp = ldsB + (size_t)col * BP + kg * 8;
            f4 a = {0.f, 0.f, 0.f, 0.f};
            #pragma unroll
            for (int ks = 0; ks < 4; ++ks)
                a = __builtin_amdgcn_mfma_f32_16x16x32_bf16(afrag[ks], *(const s8f*)(bp + ks * 32), a, 0, 0, 0);
            acc[ct] = a;
        }
        __syncthreads();

        #pragma unroll
        for (int ct = 0; ct < 8; ++ct)
            #pragma unroll
            for (int r = 0; r < 4; ++r)
                ldsS[((size_t)wv * 16 + kg * 4 + r) * SP + ct * 16 + m] = acc[ct][r];
        __syncthreads();

        #pragma unroll
        for (int p = 0; p < 4; ++p) {
            int row = p * 4 + kg;
            int rg  = r0 + row;
            if (rg < NNODES) {
                float* orow = Sp + (size_t)rg * DIM;
                #pragma unroll
                for (int j = 0; j < 2; ++j) {
                    int c0 = m * 4 + j * 64;
                    *(float4*)(orow + c0) =
                        *(const float4*)&ldsS[((size_t)wv * 16 + row) * SP + c0];
                }
            }
        }
    }

    // ---- fill store phase: sub-bucket rows [dst][xcd][8], 32B sub-rows ----
    if (doFill) {
        if (q0 < SCAP) sbuck[(size_t)d0 * SLOTS + xcd * SCAP + q0] = p0;
        else { int o = atomicAdd(ocount, 1); if (o < OCAP) obuf[o] = make_uint2((unsigned)d0, p0); }
        if (q1 < SCAP) sbuck[(size_t)d1 * SLOTS + xcd * SCAP + q1] = p1;
        else { int o = atomicAdd(ocount, 1); if (o < OCAP) obuf[o] = make_uint2((unsigned)d1, p1); }
        if (q2 < SCAP) sbuck[(size_t)d2 * SLOTS + xcd * SCAP + q2] = p2;
        else { int o = atomicAdd(ocount, 1); if (o < OCAP) obuf[o] = make_uint2((unsigned)d2, p2); }
        if (q3 < SCAP) sbuck[(size_t)d3 * SLOTS + xcd * SCAP + q3] = p3;
        else { int o = atomicAdd(ocount, 1); if (o < OCAP) obuf[o] = make_uint2((unsigned)d3, p3); }
    }
}

// ---------------------------------------------------------------------------
// gather: ONE node per wave. Lane l reads sub-bucket slot l (one coalesced
// 256B row); ballot/popc-rank compacts valid entries into LDS (divergence-
// safe — no data-carrying shfls). Batch loop: 4 entries per half per iter,
// 16 T/U loads in flight per wave. out = Sp[n] + acc/deg.
// ---------------------------------------------------------------------------
__global__ __launch_bounds__(256) void gather(
    const unsigned short* __restrict__ T, const unsigned short* __restrict__ U,
    const int* __restrict__ cnt, const unsigned* __restrict__ sbuck,
    const int* __restrict__ ocount, const uint2* __restrict__ obuf,
    const float* __restrict__ nodes, const float* __restrict__ wse,
    float* __restrict__ outp)
{
    __shared__ unsigned ldsE[4][SLOTS];
    int n = (blockIdx.x * 256 + threadIdx.x) >> 6;
    if (n >= NNODES) return;
    int wv = threadIdx.x >> 6;
    int l = threadIdx.x & 63;
    int half = l >> 5;
    int c = l & 31;

    // per-lane slot validity: xcd group = l>>3, slot = l&7
    int cx  = cnt[(size_t)(l >> 3) * NNODES + n];
    int cxc = cx < SCAP ? cx : SCAP;
    bool valid = (l & 7) < cxc;
    unsigned ent = valid ? sbuck[(size_t)n * SLOTS + l] : 0u;  // coalesced 256B
    unsigned long long mask = __ballot(valid);
    int avail = __popcll(mask);
    int rank  = __popcll(mask & ((1ull << l) - 1ull));
    if (valid) ldsE[wv][rank] = ent;   // wave-local region; lgkm wait suffices

    int deg = 0;
    #pragma unroll
    for (int i = 0; i < 8; ++i) deg += __shfl(cx, i * 8, 64);  // full activity

    float4 spm = make_float4(0.f, 0.f, 0.f, 0.f);
    if (half == 0) spm = *(const float4*)(outp + (size_t)n * DIM + c * 4);

    float4 acc = make_float4(0.f, 0.f, 0.f, 0.f);
    for (int jb = 0; jb < avail; jb += 8) {      // wave-uniform condition
        #pragma unroll
        for (int k = 0; k < 4; ++k) {
            int j = jb + k * 2 + half;
            if (j < avail) {                     // half-uniform predicate
                unsigned e = ldsE[wv][j];        // LDS broadcast read
                uint2 tt = *(const uint2*)(T + (size_t)(e & 0xFFFFu) * DIM + c * 4);
                uint2 uu = *(const uint2*)(U + (size_t)(e >> 16)     * DIM + c * 4);
                acc.x += bflo(tt.x) + bflo(uu.x); acc.y += bfhi(tt.x) + bfhi(uu.x);
                acc.z += bflo(tt.y) + bflo(uu.y); acc.w += bfhi(tt.y) + bfhi(uu.y);
            }
        }
    }

    if (deg > avail) {                           // rare overflow drain
        int oc = *ocount;
        if (oc > OCAP) oc = OCAP;
        for (int k2 = 0; k2 < oc; ++k2) {
            uint2 e2 = obuf[k2];
            if ((int)e2.x == n && (k2 & 1) == half) {
                unsigned e = e2.y;
                uint2 tt = *(const uint2*)(T + (size_t)(e & 0xFFFFu) * DIM + c * 4);
                uint2 uu = *(const uint2*)(U + (size_t)(e >> 16)     * DIM + c * 4);
                acc.x += bflo(tt.x) + bflo(uu.x); acc.y += bfhi(tt.x) + bfhi(uu.x);
                acc.z += bflo(tt.y) + bflo(uu.y); acc.w += bfhi(tt.y) + bfhi(uu.y);
            }
        }
    }

    // cross-half reduce at full-wave activity
    acc.x += __shfl_xor(acc.x, 32, 64);
    acc.y += __shfl_xor(acc.y, 32, 64);
    acc.z += __shfl_xor(acc.z, 32, 64);
    acc.w += __shfl_xor(acc.w, 32, 64);

    if (half == 0) {
        if (deg > 0) {
            float inv = 1.0f / (float)deg;
            float4 o = { spm.x + acc.x * inv, spm.y + acc.y * inv,
                         spm.z + acc.z * inv, spm.w + acc.w * inv };
            *(float4*)(outp + (size_t)n * DIM + c * 4) = o;
        } else {
            // rare (~6e-6 per node): out = h + h @ Wse
            float s0 = 0, s1 = 0, s2 = 0, s3 = 0;
            for (int k = 0; k < DIM; ++k) {
                float hk = nodes[(size_t)n * DIM + k];
                const float* wr = wse + (size_t)k * DIM + c * 4;
                s0 += hk * wr[0]; s1 += hk * wr[1];
                s2 += hk * wr[2]; s3 += hk * wr[3];
            }
            float4 hv = *(const float4*)(nodes + (size_t)n * DIM + c * 4);
            float4 o = { hv.x + s0, hv.y + s1, hv.z + s2, hv.w + s3 };
            *(float4*)(outp + (size_t)n * DIM + c * 4) = o;
        }
    }
}

// ---------------------------------------------------------------------------
extern "C" void kernel_launch(void* const* d_in, const int* in_sizes, int n_in,
                              void* d_out, int out_size, void* d_ws, size_t ws_size,
                              hipStream_t stream)
{
    const float* nodes = (const float*)d_in[0];
    const float* rels  = (const float*)d_in[1];
    const int*   edges = (const int*)d_in[2];
    const float* wn    = (const float*)d_in[3];
    const float* wsf   = (const float*)d_in[4];
    const float* wse   = (const float*)d_in[5];
    float* out = (float*)d_out;

    char* ws = (char*)d_ws;
    int*            cnt     = (int*)(ws + OFF_CNT_B);
    int*            ocount  = (int*)(ws + OFF_OCNT_B);
    uint2*          obuf    = (uint2*)(ws + OFF_OBUF_B);
    unsigned*       sbuck   = (unsigned*)(ws + OFF_SBK_B);
    unsigned short* btn     = (unsigned short*)(ws + OFF_BTN_B);
    unsigned short* bts     = (unsigned short*)(ws + OFF_BTS_B);
    unsigned short* T       = (unsigned short*)(ws + OFF_T_B);
    unsigned short* U       = (unsigned short*)(ws + OFF_U_B);

    prep<<<PREP_BLKS, 256, 0, stream>>>(wn, wsf, btn, bts, (int4*)cnt);

    fillts<<<TS_BLKS, 256, 0, stream>>>(edges, cnt, sbuck, ocount, obuf,
                                        nodes, rels, btn, bts, T, U, out);

    gather<<<GATHER_BLKS, 256, 0, stream>>>(T, U, cnt, sbuck, ocount, obuf,
                                            nodes, wse, out);
}

// Round 17
// 84.332 us; speedup vs baseline: 1.1257x; 1.1257x over previous
//
#include <hip/hip_runtime.h>

// URGCN layer, MI355X — round 17.
// r16 post-mortem: 5 fill theories ~null; gather regressed on sharded reads.
// Structural fix: replace per-edge global atomics+scatter with a two-pass
// LDS-staged counting sort (binA: coarse bins via LDS atomics + block-level
// reservation; binB: per-bin CSR build in LDS, coalesced writeout). Gather
// reverts to the proven r13 2-node form, reading true CSR.
//
// Algebra: msg_agg = (Σ_e T[src] + u[rel]) / deg, T = h@Wn (bf16 MFMA),
//          u = rel@Wn.  out = Sp + msg_agg, Sp = h@(I+Wself) (f32, in d_out).

constexpr int NNODES = 50000;
constexpr int NEDGES = 600000;
constexpr int NRELS  = 500;
constexpr int DIM    = 128;

constexpr int DPB    = 128;                        // dsts per bin
constexpr int NBIN   = (NNODES + DPB - 1) / DPB;   // 391
constexpr int BINCAP = 2048;                       // edges per bin (13 sigma)
constexpr int EPB_A  = 4096;                       // edges per binA block
constexpr int ABLK   = (NEDGES + EPB_A - 1) / EPB_A; // 147
constexpr int GSTR   = 16;                         // gcur stride (ints, 64B)
constexpr int OCAP   = 8192;

constexpr int NODE_BLKS = (NNODES + 63) / 64;   // 782
constexpr int REL_BLKS  = (NRELS  + 63) / 64;   // 8
constexpr int TS_BLKS   = NODE_BLKS + REL_BLKS; // 790

constexpr int BP = 136;   // LDS B row pitch (shorts)
constexpr int TP = 136;   // LDS T tile pitch (shorts)
constexpr int SP = 132;   // LDS S tile pitch (floats)

constexpr int WCONV_BLKS = (DIM * DIM + 255) / 256;   // 64
constexpr int ZERO_INT4S = 1604;                      // gcur + ocnt region
constexpr int ZERO_BLKS  = (ZERO_INT4S + 255) / 256;  // 7
constexpr int PREP_BLKS  = WCONV_BLKS + ZERO_BLKS;    // 71

constexpr int GATHER_BLKS = (NNODES / 2 * 64) / 256;  // 6250

// ---------------- workspace layout (bytes), ~23.1 MB ----------------
constexpr size_t OFF_GCUR_B = 0;          // int[NBIN*16] padded cursors
constexpr size_t OFF_OCNT_B = 25600;      // int
constexpr size_t OFF_OBUF_B = 25664;      // uint2[8192]
constexpr size_t OFF_OFFA_B = 91200;      // int[50000] CSR start
constexpr size_t OFF_DEGA_B = 291200;     // int[50000] binned degree
constexpr size_t OFF_EBIN_B = 491200;     // uint2[NBIN*BINCAP] 6.4MB
constexpr size_t OFF_CSR_B  = 6897344;    // uint[NBIN*BINCAP] 3.2MB
constexpr size_t OFF_BTN_B  = 10100416;   // ushort[128*128] Wn^T bf16
constexpr size_t OFF_BTS_B  = 10133184;   // ushort[128*128] (I+Ws)^T bf16
constexpr size_t OFF_T_B    = 10165952;   // ushort[50000*128]
constexpr size_t OFF_U_B    = 22965952;   // ushort[500*128]

typedef short s8f __attribute__((ext_vector_type(8)));   // 8 bf16
typedef float f4  __attribute__((ext_vector_type(4)));   // MFMA acc

static __device__ __forceinline__ unsigned short f2bf(float f) {
    unsigned u = __builtin_bit_cast(unsigned, f);
    u += 0x7FFFu + ((u >> 16) & 1u);
    return (unsigned short)(u >> 16);
}
static __device__ __forceinline__ float bflo(unsigned v) {
    return __builtin_bit_cast(float, v << 16);
}
static __device__ __forceinline__ float bfhi(unsigned v) {
    return __builtin_bit_cast(float, v & 0xFFFF0000u);
}

// ---------------------------------------------------------------------------
// prep: blocks [0,64) convert weights; blocks [64,71) zero gcur+ocnt.
__global__ __launch_bounds__(256) void prep(const float* __restrict__ wn,
                                            const float* __restrict__ wsf,
                                            unsigned short* __restrict__ btn,
                                            unsigned short* __restrict__ bts,
                                            int4* __restrict__ z4)
{
    int b = blockIdx.x;
    if (b < WCONV_BLKS) {
        int idx = b * 256 + threadIdx.x;
        int k = idx >> 7, j = idx & 127;
        btn[(size_t)j * DIM + k] = f2bf(wn[idx]);                         // Wn^T
        bts[(size_t)j * DIM + k] = f2bf(wsf[idx] + (k == j ? 1.f : 0.f)); // (I+Ws)^T
    } else {
        int idx = (b - WCONV_BLKS) * 256 + threadIdx.x;
        if (idx < ZERO_INT4S) z4[idx] = make_int4(0, 0, 0, 0);
    }
}

// ---------------------------------------------------------------------------
// binA: 4096 edges/block. LDS histogram over 391 coarse bins (LDS atomics),
// block scan, one global atomicAdd per (block,bin) to reserve space, stage
// records bin-sorted in LDS, coalesced-run writeout. Spill -> overflow list.
// ---------------------------------------------------------------------------
__global__ __launch_bounds__(256) void binA(const int* __restrict__ edges,
                                            int* __restrict__ gcur,
                                            uint2* __restrict__ ebin,
                                            int* __restrict__ ocnt,
                                            uint2* __restrict__ obuf)
{
    __shared__ int hist[512];
    __shared__ int lpre[512];
    __shared__ int base[512];
    __shared__ uint2 stage[EPB_A];   // 32 KB
    __shared__ int   gdst[EPB_A];    // 16 KB

    int t  = threadIdx.x;
    int eb = blockIdx.x * EPB_A;

    hist[t] = 0; hist[t + 256] = 0;
    __syncthreads();

    int      bin_i[16];
    int      dst_i[16];
    unsigned pay_i[16];
    int      rnk_i[16];
    #pragma unroll
    for (int i = 0; i < 16; ++i) {
        int e = eb + i * 256 + t;
        bin_i[i] = -1;
        if (e < NEDGES) {
            int s = edges[3 * e], r = edges[3 * e + 1], d = edges[3 * e + 2];
            dst_i[i] = d;
            bin_i[i] = d >> 7;
            pay_i[i] = (unsigned)s | ((unsigned)r << 16);
            rnk_i[i] = atomicAdd(&hist[bin_i[i]], 1);
        }
    }
    __syncthreads();

    // inclusive Hillis-Steele over 512 (2 elems/thread), then excl = lpre-hist
    lpre[t] = hist[t]; lpre[t + 256] = hist[t + 256];
    __syncthreads();
    for (int d = 1; d < 512; d <<= 1) {
        int a0 = (t >= d) ? lpre[t - d] : 0;
        int a1 = lpre[t + 256 - d];          // t+256 >= d always (d<=256)
        __syncthreads();
        lpre[t] += a0; lpre[t + 256] += a1;
        __syncthreads();
    }

    // reserve global bin space (one atomic per nonempty bin per block)
    if (t < NBIN && hist[t] > 0)
        base[t] = atomicAdd(gcur + (size_t)t * GSTR, hist[t]);
    if (t + 256 < NBIN && hist[t + 256] > 0)
        base[t + 256] = atomicAdd(gcur + (size_t)(t + 256) * GSTR, hist[t + 256]);
    __syncthreads();

    // stage records ordered by (bin, rank); precompute global destination
    #pragma unroll
    for (int i = 0; i < 16; ++i) {
        if (bin_i[i] >= 0) {
            int b  = bin_i[i];
            int lp = (lpre[b] - hist[b]) + rnk_i[i];
            stage[lp] = make_uint2((unsigned)dst_i[i], pay_i[i]);
            int q = base[b] + rnk_i[i];
            gdst[lp] = (q < BINCAP) ? (b * BINCAP + q) : -1;
        }
    }
    __syncthreads();

    int ne = NEDGES - eb; if (ne > EPB_A) ne = EPB_A;
    for (int j = t; j < ne; j += 256) {
        int g = gdst[j];
        uint2 rec = stage[j];
        if (g >= 0) ebin[g] = rec;
        else { int o = atomicAdd(ocnt, 1); if (o < OCAP) obuf[o] = rec; }
    }
}

// ---------------------------------------------------------------------------
// binB: one block per bin. Build the bin's CSR in LDS (count, scan, scatter),
// write the CSR segment + off/deg fully coalesced. No global atomics.
// ---------------------------------------------------------------------------
__global__ __launch_bounds__(256) void binB(const int* __restrict__ gcur,
                                            const uint2* __restrict__ ebin,
                                            unsigned* __restrict__ csr,
                                            int* __restrict__ offa,
                                            int* __restrict__ dega)
{
    __shared__ int cnt[DPB];
    __shared__ int loff[DPB];
    __shared__ unsigned tpay[BINCAP];    // 8 KB
    __shared__ short    tdl[BINCAP];     // 4 KB
    __shared__ short    trk[BINCAP];     // 4 KB
    __shared__ unsigned pays[BINCAP];    // 8 KB

    int bin = blockIdx.x;
    int t   = threadIdx.x;
    int totraw = gcur[(size_t)bin * GSTR];
    int total  = totraw < BINCAP ? totraw : BINCAP;

    if (t < DPB) cnt[t] = 0;
    __syncthreads();

    for (int j = t; j < total; j += 256) {
        uint2 rec = ebin[(size_t)bin * BINCAP + j];
        int dl = (int)(rec.x & (DPB - 1));
        tdl[j]  = (short)dl;
        tpay[j] = rec.y;
        trk[j]  = (short)atomicAdd(&cnt[dl], 1);
    }
    __syncthreads();

    if (t < DPB) loff[t] = cnt[t];
    __syncthreads();
    for (int d = 1; d < DPB; d <<= 1) {
        int a0 = 0;
        if (t < DPB && t >= d) a0 = loff[t - d];
        __syncthreads();
        if (t < DPB) loff[t] += a0;
        __syncthreads();
    }
    // loff inclusive; exclusive = loff - cnt

    for (int j = t; j < total; j += 256) {
        int dl = tdl[j];
        pays[(loff[dl] - cnt[dl]) + trk[j]] = tpay[j];
    }
    __syncthreads();

    for (int j = t; j < total; j += 256)
        csr[(size_t)bin * BINCAP + j] = pays[j];

    int n = bin * DPB + t;
    if (t < DPB && n < NNODES) {
        offa[n] = bin * BINCAP + (loff[t] - cnt[t]);
        dega[n] = cnt[t];
    }
}

// ---------------------------------------------------------------------------
// ts_kernel: fused two-phase GEMM, ONE aliased LDS buffer (34.8 KB), 4 blk/CU.
// (r13 proven form.)
// ---------------------------------------------------------------------------
__global__ __launch_bounds__(256, 4) void ts_kernel(
    const float* __restrict__ nodes, const float* __restrict__ rels,
    const unsigned short* __restrict__ btn, const unsigned short* __restrict__ bts,
    unsigned short* __restrict__ T, unsigned short* __restrict__ U,
    float* __restrict__ Sp)
{
    __shared__ __align__(16) char ldsRaw[DIM * BP * 2];   // 34816 B
    unsigned short* ldsB = (unsigned short*)ldsRaw;
    unsigned short* ldsT = (unsigned short*)ldsRaw;
    float*          ldsS = (float*)ldsRaw;

    int blk = blockIdx.x;
    bool isRel = blk >= NODE_BLKS;
    const float* A = isRel ? rels : nodes;
    int nrows = isRel ? NRELS : NNODES;
    int rowbase = (isRel ? (blk - NODE_BLKS) : blk) * 64;

    int t  = threadIdx.x;
    int wv = t >> 6;
    int l  = t & 63;
    int r0 = rowbase + wv * 16;
    int m  = l & 15;
    int kg = l >> 4;
    int arow  = r0 + m;
    int arowc = arow < nrows ? arow : nrows - 1;

    s8f afrag[4];
    #pragma unroll
    for (int ks = 0; ks < 4; ++ks) {
        const float* p = A + (size_t)arowc * DIM + ks * 32 + kg * 8;
        float4 x = *(const float4*)p;
        float4 y = *(const float4*)(p + 4);
        s8f a;
        a[0] = (short)f2bf(x.x); a[1] = (short)f2bf(x.y);
        a[2] = (short)f2bf(x.z); a[3] = (short)f2bf(x.w);
        a[4] = (short)f2bf(y.x); a[5] = (short)f2bf(y.y);
        a[6] = (short)f2bf(y.z); a[7] = (short)f2bf(y.w);
        afrag[ks] = a;
    }

    // phase 1: T/U = A @ Wn
    #pragma unroll
    for (int i = 0; i < 8; ++i) {
        int idx = t + i * 256;
        int col = idx >> 4, slot = idx & 15;
        *(uint4*)(ldsB + (size_t)col * BP + slot * 8) =
            *(const uint4*)(btn + (size_t)col * DIM + slot * 8);
    }
    __syncthreads();

    f4 acc[8];
    #pragma unroll
    for (int ct = 0; ct < 8; ++ct) {
        int col = ct * 16 + m;
        const unsigned short* bp = ldsB + (size_t)col * BP + kg * 8;
        f4 a = {0.f, 0.f, 0.f, 0.f};
        #pragma unroll
        for (int ks = 0; ks < 4; ++ks)
            a = __builtin_amdgcn_mfma_f32_16x16x32_bf16(afrag[ks], *(const s8f*)(bp + ks * 32), a, 0, 0, 0);
        acc[ct] = a;
    }
    __syncthreads();

    #pragma unroll
    for (int ct = 0; ct < 8; ++ct)
        #pragma unroll
        for (int r = 0; r < 4; ++r)
            ldsT[((size_t)wv * 16 + kg * 4 + r) * TP + ct * 16 + m] = f2bf(acc[ct][r]);
    __syncthreads();

    unsigned short* Tout = isRel ? U : T;
    #pragma unroll
    for (int p = 0; p < 4; ++p) {
        int row = p * 4 + kg;
        int rg  = r0 + row;
        if (rg < nrows)
            *(uint4*)(Tout + (size_t)rg * DIM + m * 8) =
                *(const uint4*)&ldsT[((size_t)wv * 16 + row) * TP + m * 8];
    }
    if (isRel) return;

    __syncthreads();

    // phase 2: Sp = A @ (I+Ws)
    #pragma unroll
    for (int i = 0; i < 8; ++i) {
        int idx = t + i * 256;
        int col = idx >> 4, slot = idx & 15;
        *(uint4*)(ldsB + (size_t)col * BP + slot * 8) =
            *(const uint4*)(bts + (size_t)col * DIM + slot * 8);
    }
    __syncthreads();

    #pragma unroll
    for (int ct = 0; ct < 8; ++ct) {
        int col = ct * 16 + m;
        const unsigned short* bp = ldsB + (size_t)col * BP + kg * 8;
        f4 a = {0.f, 0.f, 0.f, 0.f};
        #pragma unroll
        for (int ks = 0; ks < 4; ++ks)
            a = __builtin_amdgcn_mfma_f32_16x16x32_bf16(afrag[ks], *(const s8f*)(bp + ks * 32), a, 0, 0, 0);
        acc[ct] = a;
    }
    __syncthreads();

    #pragma unroll
    for (int ct = 0; ct < 8; ++ct)
        #pragma unroll
        for (int r = 0; r < 4; ++r)
            ldsS[((size_t)wv * 16 + kg * 4 + r) * SP + ct * 16 + m] = acc[ct][r];
    __syncthreads();

    #pragma unroll
    for (int p = 0; p < 4; ++p) {
        int row = p * 4 + kg;
        int rg  = r0 + row;
        if (rg < NNODES) {
            float* orow = Sp + (size_t)rg * DIM;
            #pragma unroll
            for (int j = 0; j < 2; ++j) {
                int c0 = m * 4 + j * 64;
                *(float4*)(orow + c0) =
                    *(const float4*)&ldsS[((size_t)wv * 16 + row) * SP + c0];
            }
        }
    }
}

// ---------------------------------------------------------------------------
// gather: TWO nodes per wave, CSR input (r13 proven structure).
// ---------------------------------------------------------------------------
#define ACCP(A, b) { \
    uint2 tt = *(const uint2*)(T + (size_t)((b) & 0xFFFFu) * DIM + c * 4); \
    uint2 uu = *(const uint2*)(U + (size_t)((b) >> 16)     * DIM + c * 4); \
    A.x += bflo(tt.x) + bflo(uu.x); A.y += bfhi(tt.x) + bfhi(uu.x); \
    A.z += bflo(tt.y) + bflo(uu.y); A.w += bfhi(tt.y) + bfhi(uu.y); }

#define BATCH(my, degc, A) \
    if (jb < degc) { \
        unsigned b0 = __shfl(my, j0,     64); \
        unsigned b1 = __shfl(my, j0 + 2, 64); \
        unsigned b2 = __shfl(my, j0 + 4, 64); \
        unsigned b3 = __shfl(my, j0 + 6, 64); \
        if (jb + 8 <= degc) { ACCP(A, b0); ACCP(A, b1); ACCP(A, b2); ACCP(A, b3); } \
        else { \
            if (j0     < degc) ACCP(A, b0); \
            if (j0 + 2 < degc) ACCP(A, b1); \
            if (j0 + 4 < degc) ACCP(A, b2); \
            if (j0 + 6 < degc) ACCP(A, b3); } }

__global__ __launch_bounds__(256) void gather(
    const unsigned short* __restrict__ T, const unsigned short* __restrict__ U,
    const int* __restrict__ offa, const int* __restrict__ dega,
    const unsigned* __restrict__ csr,
    const int* __restrict__ ocnt, const uint2* __restrict__ obuf,
    const float* __restrict__ nodes, const float* __restrict__ wse,
    float* __restrict__ outp)
{
    int wid = (blockIdx.x * 256 + threadIdx.x) >> 6;
    if (wid >= NNODES / 2) return;
    int n0 = wid * 2;
    int n1 = n0 + 1;
    int l = threadIdx.x & 63;
    int half = l >> 5;
    int c = l & 31;

    int deg0 = dega[n0];                 // wave-uniform (binned degree)
    int deg1 = dega[n1];
    int beg0 = offa[n0];
    int beg1 = offa[n1];
    int degc0 = deg0 < 64 ? deg0 : 64;
    int degc1 = deg1 < 64 ? deg1 : 64;

    unsigned my0 = (l < degc0) ? csr[(size_t)beg0 + l] : 0u;
    unsigned my1 = (l < degc1) ? csr[(size_t)beg1 + l] : 0u;
    int nm = half ? n1 : n0;
    float4 spm = *(const float4*)(outp + (size_t)nm * DIM + c * 4);

    float4 acc0 = make_float4(0.f, 0.f, 0.f, 0.f);
    float4 acc1 = make_float4(0.f, 0.f, 0.f, 0.f);
    int maxd = degc0 > degc1 ? degc0 : degc1;
    for (int jb = 0; jb < maxd; jb += 8) {   // wave-uniform condition
        int j0 = jb + half;
        BATCH(my0, degc0, acc0);
        BATCH(my1, degc1, acc1);
    }

    // binned entries beyond 64 (~never; Poisson(12)) — loads only, safe
    for (int j = 64 + half; j < deg0; j += 2) ACCP(acc0, csr[(size_t)beg0 + j]);
    for (int j = 64 + half; j < deg1; j += 2) ACCP(acc1, csr[(size_t)beg1 + j]);

    // overflow drain (~never): count matches into the divisor too
    int dt0 = 0, dt1 = 0;
    int oc = *ocnt;
    if (oc > 0) {                            // wave-uniform
        if (oc > OCAP) oc = OCAP;
        for (int k = 0; k < oc; ++k) {
            uint2 e = obuf[k];
            if ((int)e.x == n0) { dt0++; if ((k & 1) == half) ACCP(acc0, e.y); }
            if ((int)e.x == n1) { dt1++; if ((k & 1) == half) ACCP(acc1, e.y); }
        }
    }
    int degt0 = deg0 + dt0;
    int degt1 = deg1 + dt1;

    acc0.x += __shfl_xor(acc0.x, 32, 64);
    acc0.y += __shfl_xor(acc0.y, 32, 64);
    acc0.z += __shfl_xor(acc0.z, 32, 64);
    acc0.w += __shfl_xor(acc0.w, 32, 64);
    acc1.x += __shfl_xor(acc1.x, 32, 64);
    acc1.y += __shfl_xor(acc1.y, 32, 64);
    acc1.z += __shfl_xor(acc1.z, 32, 64);
    acc1.w += __shfl_xor(acc1.w, 32, 64);

    float4 am = half ? acc1 : acc0;
    int dm = half ? degt1 : degt0;
    if (dm > 0) {
        float inv = 1.0f / (float)dm;
        float4 o = { spm.x + am.x * inv, spm.y + am.y * inv,
                     spm.z + am.z * inv, spm.w + am.w * inv };
        *(float4*)(outp + (size_t)nm * DIM + c * 4) = o;
    }

    if (degt0 == 0 && half == 0) {
        float s0 = 0, s1 = 0, s2 = 0, s3 = 0;
        for (int k = 0; k < DIM; ++k) {
            float hk = nodes[(size_t)n0 * DIM + k];
            const float* wr = wse + (size_t)k * DIM + c * 4;
            s0 += hk * wr[0]; s1 += hk * wr[1];
            s2 += hk * wr[2]; s3 += hk * wr[3];
        }
        float4 hv = *(const float4*)(nodes + (size_t)n0 * DIM + c * 4);
        float4 o = { hv.x + s0, hv.y + s1, hv.z + s2, hv.w + s3 };
        *(float4*)(outp + (size_t)n0 * DIM + c * 4) = o;
    }
    if (degt1 == 0 && half == 1) {
        float s0 = 0, s1 = 0, s2 = 0, s3 = 0;
        for (int k = 0; k < DIM; ++k) {
            float hk = nodes[(size_t)n1 * DIM + k];
            const float* wr = wse + (size_t)k * DIM + c * 4;
            s0 += hk * wr[0]; s1 += hk * wr[1];
            s2 += hk * wr[2]; s3 += hk * wr[3];
        }
        float4 hv = *(const float4*)(nodes + (size_t)n1 * DIM + c * 4);
        float4 o = { hv.x + s0, hv.y + s1, hv.z + s2, hv.w + s3 };
        *(float4*)(outp + (size_t)n1 * DIM + c * 4) = o;
    }
}

// ---------------------------------------------------------------------------
extern "C" void kernel_launch(void* const* d_in, const int* in_sizes, int n_in,
                              void* d_out, int out_size, void* d_ws, size_t ws_size,
                              hipStream_t stream)
{
    const float* nodes = (const float*)d_in[0];
    const float* rels  = (const float*)d_in[1];
    const int*   edges = (const int*)d_in[2];
    const float* wn    = (const float*)d_in[3];
    const float* wsf   = (const float*)d_in[4];
    const float* wse   = (const float*)d_in[5];
    float* out = (float*)d_out;

    char* ws = (char*)d_ws;
    int*            gcur  = (int*)(ws + OFF_GCUR_B);
    int*            ocnt  = (int*)(ws + OFF_OCNT_B);
    uint2*          obuf  = (uint2*)(ws + OFF_OBUF_B);
    int*            offa  = (int*)(ws + OFF_OFFA_B);
    int*            dega  = (int*)(ws + OFF_DEGA_B);
    uint2*          ebin  = (uint2*)(ws + OFF_EBIN_B);
    unsigned*       csr   = (unsigned*)(ws + OFF_CSR_B);
    unsigned short* btn   = (unsigned short*)(ws + OFF_BTN_B);
    unsigned short* bts   = (unsigned short*)(ws + OFF_BTS_B);
    unsigned short* T     = (unsigned short*)(ws + OFF_T_B);
    unsigned short* U     = (unsigned short*)(ws + OFF_U_B);

    prep<<<PREP_BLKS, 256, 0, stream>>>(wn, wsf, btn, bts, (int4*)gcur);

    binA<<<ABLK, 256, 0, stream>>>(edges, gcur, ebin, ocnt, obuf);
    binB<<<NBIN, 256, 0, stream>>>(gcur, ebin, csr, offa, dega);

    ts_kernel<<<TS_BLKS, 256, 0, stream>>>(nodes, rels, btn, bts, T, U, out);

    gather<<<GATHER_BLKS, 256, 0, stream>>>(T, U, offa, dega, csr, ocnt, obuf,
                                            nodes, wse, out);
}

// Round 18
// 74.258 us; speedup vs baseline: 1.2784x; 1.1357x over previous
//
#include <hip/hip_runtime.h>

// URGCN layer, MI355X — round 18.
// r17 post-mortem: counting sort worked (84us); gather (~43us) is now the
// program — memory-throughput-bound on the random 256B T-row stream
// (153.6MB over a 12.8MB region; ~8.4 TB/s aggregate observed). Fix: T in
// fp8 e4m3 (128B rows) via gfx950 OCP fp8 HW converts (guarded builtins,
// software RNE fallback). U stays bf16 (L2-resident, halves added error).
//
// Algebra: msg_agg = (Σ_e T[src] + u[rel]) / deg, T = h@Wn (fp8 store),
//          u = rel@Wn (bf16).  out = Sp + msg_agg, Sp = h@(I+Wself) (f32).

constexpr int NNODES = 50000;
constexpr int NEDGES = 600000;
constexpr int NRELS  = 500;
constexpr int DIM    = 128;

constexpr int DPB    = 128;                        // dsts per bin
constexpr int NBIN   = (NNODES + DPB - 1) / DPB;   // 391
constexpr int BINCAP = 2048;                       // edges per bin (13 sigma)
constexpr int EPB_A  = 4096;                       // edges per binA block
constexpr int ABLK   = (NEDGES + EPB_A - 1) / EPB_A; // 147
constexpr int GSTR   = 16;                         // gcur stride (ints, 64B)
constexpr int OCAP   = 8192;

constexpr int NODE_BLKS = (NNODES + 63) / 64;   // 782
constexpr int REL_BLKS  = (NRELS  + 63) / 64;   // 8
constexpr int TS_BLKS   = NODE_BLKS + REL_BLKS; // 790

constexpr int BP = 136;   // LDS B row pitch (shorts)
constexpr int SP = 132;   // LDS f32 tile pitch (floats)

constexpr int WCONV_BLKS = (DIM * DIM + 255) / 256;   // 64
constexpr int ZERO_INT4S = 1604;                      // gcur + ocnt region
constexpr int ZERO_BLKS  = (ZERO_INT4S + 255) / 256;  // 7
constexpr int PREP_BLKS  = WCONV_BLKS + ZERO_BLKS;    // 71

constexpr int GATHER_BLKS = (NNODES / 2 * 64) / 256;  // 6250

// ---------------- workspace layout (bytes) ----------------
constexpr size_t OFF_GCUR_B = 0;          // int[NBIN*16] padded cursors
constexpr size_t OFF_OCNT_B = 25600;      // int
constexpr size_t OFF_OBUF_B = 25664;      // uint2[8192]
constexpr size_t OFF_OFFA_B = 91200;      // int[50000] CSR start
constexpr size_t OFF_DEGA_B = 291200;     // int[50000] binned degree
constexpr size_t OFF_EBIN_B = 491200;     // uint2[NBIN*BINCAP] 6.4MB
constexpr size_t OFF_CSR_B  = 6897344;    // uint[NBIN*BINCAP] 3.2MB
constexpr size_t OFF_BTN_B  = 10100416;   // ushort[128*128] Wn^T bf16
constexpr size_t OFF_BTS_B  = 10133184;   // ushort[128*128] (I+Ws)^T bf16
constexpr size_t OFF_T_B    = 10165952;   // uchar[50000*128] fp8 T (6.4MB)
constexpr size_t OFF_U_B    = 22965952;   // ushort[500*128] bf16 U

typedef short s8f __attribute__((ext_vector_type(8)));   // 8 bf16
typedef float f4  __attribute__((ext_vector_type(4)));   // MFMA acc

static __device__ __forceinline__ unsigned short f2bf(float f) {
    unsigned u = __builtin_bit_cast(unsigned, f);
    u += 0x7FFFu + ((u >> 16) & 1u);
    return (unsigned short)(u >> 16);
}
static __device__ __forceinline__ float bflo(unsigned v) {
    return __builtin_bit_cast(float, v << 16);
}
static __device__ __forceinline__ float bfhi(unsigned v) {
    return __builtin_bit_cast(float, v & 0xFFFF0000u);
}

// ---- fp8 e4m3 pack/unpack (HW converts when available) ----
static __device__ __forceinline__ void dec_fp8x4(unsigned w, float* f) {
#if __has_builtin(__builtin_amdgcn_cvt_pk_f32_fp8)
    typedef float f2v __attribute__((ext_vector_type(2)));
    f2v lo = __builtin_amdgcn_cvt_pk_f32_fp8((int)w, false);
    f2v hi = __builtin_amdgcn_cvt_pk_f32_fp8((int)w, true);
    f[0] = lo[0]; f[1] = lo[1]; f[2] = hi[0]; f[3] = hi[1];
#else
    #pragma unroll
    for (int i = 0; i < 4; ++i) {
        unsigned b = (w >> (8 * i)) & 0xFFu;
        unsigned e = (b >> 3) & 15u, m = b & 7u;
        float v = e ? __builtin_bit_cast(float, ((e + 120u) << 23) | (m << 20))
                    : (float)m * 0.001953125f;          // m * 2^-9
        f[i] = (b & 0x80u) ? -v : v;
    }
#endif
}
static __device__ __forceinline__ unsigned enc_fp8x4(float a, float b,
                                                     float cc, float d) {
#if __has_builtin(__builtin_amdgcn_cvt_pk_fp8_f32)
    int w = __builtin_amdgcn_cvt_pk_fp8_f32(a, b, 0, false);
    w = __builtin_amdgcn_cvt_pk_fp8_f32(cc, d, w, true);
    return (unsigned)w;
#else
    float vv[4] = {a, b, cc, d};
    unsigned w = 0;
    #pragma unroll
    for (int i = 0; i < 4; ++i) {
        unsigned u = __builtin_bit_cast(unsigned, vv[i]);
        unsigned s = u >> 31;
        unsigned au = u & 0x7FFFFFFFu;
        float af = __builtin_bit_cast(float, au);
        unsigned byte;
        if (af < 0.015625f) byte = s << 7;              // flush subnormal
        else {
            if (af > 448.f) au = 0x43E00000u;           // clamp to 448
            unsigned lsb = (au >> 20) & 1u;
            au += 0x7FFFFu + lsb;                       // RNE at 3 mant bits
            int e8 = (int)(au >> 23) - 120;
            unsigned m3 = (au >> 20) & 7u;
            if (e8 > 15) { e8 = 15; m3 = 6; }
            byte = (s << 7) | ((unsigned)e8 << 3) | m3;
        }
        w |= byte << (8 * i);
    }
    return w;
#endif
}

// ---------------------------------------------------------------------------
// prep: blocks [0,64) convert weights; blocks [64,71) zero gcur+ocnt.
__global__ __launch_bounds__(256) void prep(const float* __restrict__ wn,
                                            const float* __restrict__ wsf,
                                            unsigned short* __restrict__ btn,
                                            unsigned short* __restrict__ bts,
                                            int4* __restrict__ z4)
{
    int b = blockIdx.x;
    if (b < WCONV_BLKS) {
        int idx = b * 256 + threadIdx.x;
        int k = idx >> 7, j = idx & 127;
        btn[(size_t)j * DIM + k] = f2bf(wn[idx]);                         // Wn^T
        bts[(size_t)j * DIM + k] = f2bf(wsf[idx] + (k == j ? 1.f : 0.f)); // (I+Ws)^T
    } else {
        int idx = (b - WCONV_BLKS) * 256 + threadIdx.x;
        if (idx < ZERO_INT4S) z4[idx] = make_int4(0, 0, 0, 0);
    }
}

// ---------------------------------------------------------------------------
// binA: 4096 edges/block. LDS histogram over coarse bins, block scan, one
// global atomicAdd per (block,bin), staged bin-sorted writeout. (r17 form.)
// ---------------------------------------------------------------------------
__global__ __launch_bounds__(256) void binA(const int* __restrict__ edges,
                                            int* __restrict__ gcur,
                                            uint2* __restrict__ ebin,
                                            int* __restrict__ ocnt,
                                            uint2* __restrict__ obuf)
{
    __shared__ int hist[512];
    __shared__ int lpre[512];
    __shared__ int base[512];
    __shared__ uint2 stage[EPB_A];   // 32 KB
    __shared__ int   gdst[EPB_A];    // 16 KB

    int t  = threadIdx.x;
    int eb = blockIdx.x * EPB_A;

    hist[t] = 0; hist[t + 256] = 0;
    __syncthreads();

    int      bin_i[16];
    int      dst_i[16];
    unsigned pay_i[16];
    int      rnk_i[16];
    #pragma unroll
    for (int i = 0; i < 16; ++i) {
        int e = eb + i * 256 + t;
        bin_i[i] = -1;
        if (e < NEDGES) {
            int s = edges[3 * e], r = edges[3 * e + 1], d = edges[3 * e + 2];
            dst_i[i] = d;
            bin_i[i] = d >> 7;
            pay_i[i] = (unsigned)s | ((unsigned)r << 16);
            rnk_i[i] = atomicAdd(&hist[bin_i[i]], 1);
        }
    }
    __syncthreads();

    lpre[t] = hist[t]; lpre[t + 256] = hist[t + 256];
    __syncthreads();
    for (int d = 1; d < 512; d <<= 1) {
        int a0 = (t >= d) ? lpre[t - d] : 0;
        int a1 = lpre[t + 256 - d];
        __syncthreads();
        lpre[t] += a0; lpre[t + 256] += a1;
        __syncthreads();
    }

    if (t < NBIN && hist[t] > 0)
        base[t] = atomicAdd(gcur + (size_t)t * GSTR, hist[t]);
    if (t + 256 < NBIN && hist[t + 256] > 0)
        base[t + 256] = atomicAdd(gcur + (size_t)(t + 256) * GSTR, hist[t + 256]);
    __syncthreads();

    #pragma unroll
    for (int i = 0; i < 16; ++i) {
        if (bin_i[i] >= 0) {
            int b  = bin_i[i];
            int lp = (lpre[b] - hist[b]) + rnk_i[i];
            stage[lp] = make_uint2((unsigned)dst_i[i], pay_i[i]);
            int q = base[b] + rnk_i[i];
            gdst[lp] = (q < BINCAP) ? (b * BINCAP + q) : -1;
        }
    }
    __syncthreads();

    int ne = NEDGES - eb; if (ne > EPB_A) ne = EPB_A;
    for (int j = t; j < ne; j += 256) {
        int g = gdst[j];
        uint2 rec = stage[j];
        if (g >= 0) ebin[g] = rec;
        else { int o = atomicAdd(ocnt, 1); if (o < OCAP) obuf[o] = rec; }
    }
}

// ---------------------------------------------------------------------------
// binB: one block per bin. CSR build in LDS, coalesced writeout. (r17 form.)
// ---------------------------------------------------------------------------
__global__ __launch_bounds__(256) void binB(const int* __restrict__ gcur,
                                            const uint2* __restrict__ ebin,
                                            unsigned* __restrict__ csr,
                                            int* __restrict__ offa,
                                            int* __restrict__ dega)
{
    __shared__ int cnt[DPB];
    __shared__ int loff[DPB];
    __shared__ unsigned tpay[BINCAP];
    __shared__ short    tdl[BINCAP];
    __shared__ short    trk[BINCAP];
    __shared__ unsigned pays[BINCAP];

    int bin = blockIdx.x;
    int t   = threadIdx.x;
    int totraw = gcur[(size_t)bin * GSTR];
    int total  = totraw < BINCAP ? totraw : BINCAP;

    if (t < DPB) cnt[t] = 0;
    __syncthreads();

    for (int j = t; j < total; j += 256) {
        uint2 rec = ebin[(size_t)bin * BINCAP + j];
        int dl = (int)(rec.x & (DPB - 1));
        tdl[j]  = (short)dl;
        tpay[j] = rec.y;
        trk[j]  = (short)atomicAdd(&cnt[dl], 1);
    }
    __syncthreads();

    if (t < DPB) loff[t] = cnt[t];
    __syncthreads();
    for (int d = 1; d < DPB; d <<= 1) {
        int a0 = 0;
        if (t < DPB && t >= d) a0 = loff[t - d];
        __syncthreads();
        if (t < DPB) loff[t] += a0;
        __syncthreads();
    }

    for (int j = t; j < total; j += 256) {
        int dl = tdl[j];
        pays[(loff[dl] - cnt[dl]) + trk[j]] = tpay[j];
    }
    __syncthreads();

    for (int j = t; j < total; j += 256)
        csr[(size_t)bin * BINCAP + j] = pays[j];

    int n = bin * DPB + t;
    if (t < DPB && n < NNODES) {
        offa[n] = bin * BINCAP + (loff[t] - cnt[t]);
        dega[n] = cnt[t];
    }
}

// ---------------------------------------------------------------------------
// ts_kernel: fused two-phase GEMM, ONE aliased LDS buffer, 4 blk/CU.
// Phase-1 results staged f32 in LDS; epilogue packs fp8 (T) / bf16 (U).
// ---------------------------------------------------------------------------
__global__ __launch_bounds__(256, 4) void ts_kernel(
    const float* __restrict__ nodes, const float* __restrict__ rels,
    const unsigned short* __restrict__ btn, const unsigned short* __restrict__ bts,
    unsigned char* __restrict__ T8, unsigned short* __restrict__ U,
    float* __restrict__ Sp)
{
    __shared__ __align__(16) char ldsRaw[DIM * BP * 2];   // 34816 B
    unsigned short* ldsB = (unsigned short*)ldsRaw;
    float*          ldsS = (float*)ldsRaw;                // aliased f32 tile

    int blk = blockIdx.x;
    bool isRel = blk >= NODE_BLKS;
    const float* A = isRel ? rels : nodes;
    int nrows = isRel ? NRELS : NNODES;
    int rowbase = (isRel ? (blk - NODE_BLKS) : blk) * 64;

    int t  = threadIdx.x;
    int wv = t >> 6;
    int l  = t & 63;
    int r0 = rowbase + wv * 16;
    int m  = l & 15;
    int kg = l >> 4;
    int arow  = r0 + m;
    int arowc = arow < nrows ? arow : nrows - 1;

    s8f afrag[4];
    #pragma unroll
    for (int ks = 0; ks < 4; ++ks) {
        const float* p = A + (size_t)arowc * DIM + ks * 32 + kg * 8;
        float4 x = *(const float4*)p;
        float4 y = *(const float4*)(p + 4);
        s8f a;
        a[0] = (short)f2bf(x.x); a[1] = (short)f2bf(x.y);
        a[2] = (short)f2bf(x.z); a[3] = (short)f2bf(x.w);
        a[4] = (short)f2bf(y.x); a[5] = (short)f2bf(y.y);
        a[6] = (short)f2bf(y.z); a[7] = (short)f2bf(y.w);
        afrag[ks] = a;
    }

    // phase 1: A @ Wn -> f32 LDS tile
    #pragma unroll
    for (int i = 0; i < 8; ++i) {
        int idx = t + i * 256;
        int col = idx >> 4, slot = idx & 15;
        *(uint4*)(ldsB + (size_t)col * BP + slot * 8) =
            *(const uint4*)(btn + (size_t)col * DIM + slot * 8);
    }
    __syncthreads();

    f4 acc[8];
    #pragma unroll
    for (int ct = 0; ct < 8; ++ct) {
        int col = ct * 16 + m;
        const unsigned short* bp = ldsB + (size_t)col * BP + kg * 8;
        f4 a = {0.f, 0.f, 0.f, 0.f};
        #pragma unroll
        for (int ks = 0; ks < 4; ++ks)
            a = __builtin_amdgcn_mfma_f32_16x16x32_bf16(afrag[ks], *(const s8f*)(bp + ks * 32), a, 0, 0, 0);
        acc[ct] = a;
    }
    __syncthreads();   // ldsB reads done; overwrite as f32 tile

    #pragma unroll
    for (int ct = 0; ct < 8; ++ct)
        #pragma unroll
        for (int r = 0; r < 4; ++r)
            ldsS[((size_t)wv * 16 + kg * 4 + r) * SP + ct * 16 + m] = acc[ct][r];
    __syncthreads();

    #pragma unroll
    for (int p = 0; p < 4; ++p) {
        int row = p * 4 + kg;
        int rg  = r0 + row;
        if (rg < nrows) {
            const float* rp = &ldsS[((size_t)wv * 16 + row) * SP + m * 8];
            float4 x = *(const float4*)rp;
            float4 y = *(const float4*)(rp + 4);
            if (!isRel) {
                uint2 o = { enc_fp8x4(x.x, x.y, x.z, x.w),
                            enc_fp8x4(y.x, y.y, y.z, y.w) };
                *(uint2*)(T8 + (size_t)rg * DIM + m * 8) = o;
            } else {
                uint4 o;
                o.x = (unsigned)f2bf(x.x) | ((unsigned)f2bf(x.y) << 16);
                o.y = (unsigned)f2bf(x.z) | ((unsigned)f2bf(x.w) << 16);
                o.z = (unsigned)f2bf(y.x) | ((unsigned)f2bf(y.y) << 16);
                o.w = (unsigned)f2bf(y.z) | ((unsigned)f2bf(y.w) << 16);
                *(uint4*)(U + (size_t)rg * DIM + m * 8) = o;
            }
        }
    }
    if (isRel) return;

    __syncthreads();

    // phase 2: Sp = A @ (I+Ws)
    #pragma unroll
    for (int i = 0; i < 8; ++i) {
        int idx = t + i * 256;
        int col = idx >> 4, slot = idx & 15;
        *(uint4*)(ldsB + (size_t)col * BP + slot * 8) =
            *(const uint4*)(bts + (size_t)col * DIM + slot * 8);
    }
    __syncthreads();

    #pragma unroll
    for (int ct = 0; ct < 8; ++ct) {
        int col = ct * 16 + m;
        const unsigned short* bp = ldsB + (size_t)col * BP + kg * 8;
        f4 a = {0.f, 0.f, 0.f, 0.f};
        #pragma unroll
        for (int ks = 0; ks < 4; ++ks)
            a = __builtin_amdgcn_mfma_f32_16x16x32_bf16(afrag[ks], *(const s8f*)(bp + ks * 32), a, 0, 0, 0);
        acc[ct] = a;
    }
    __syncthreads();

    #pragma unroll
    for (int ct = 0; ct < 8; ++ct)
        #pragma unroll
        for (int r = 0; r < 4; ++r)
            ldsS[((size_t)wv * 16 + kg * 4 + r) * SP + ct * 16 + m] = acc[ct][r];
    __syncthreads();

    #pragma unroll
    for (int p = 0; p < 4; ++p) {
        int row = p * 4 + kg;
        int rg  = r0 + row;
        if (rg < NNODES) {
            float* orow = Sp + (size_t)rg * DIM;
            #pragma unroll
            for (int j = 0; j < 2; ++j) {
                int c0 = m * 4 + j * 64;
                *(float4*)(orow + c0) =
                    *(const float4*)&ldsS[((size_t)wv * 16 + row) * SP + c0];
            }
        }
    }
}

// ---------------------------------------------------------------------------
// gather: TWO nodes per wave, CSR input (r13 structure), fp8 T + bf16 U.
// ---------------------------------------------------------------------------
#define ACCP(A, b) { \
    unsigned tw = *(const unsigned*)(T8 + (size_t)((b) & 0xFFFFu) * DIM + c * 4); \
    uint2 uu = *(const uint2*)(U + (size_t)((b) >> 16) * DIM + c * 4); \
    float tf[4]; dec_fp8x4(tw, tf); \
    A.x += tf[0] + bflo(uu.x); A.y += tf[1] + bfhi(uu.x); \
    A.z += tf[2] + bflo(uu.y); A.w += tf[3] + bfhi(uu.y); }

#define BATCH(my, degc, A) \
    if (jb < degc) { \
        unsigned b0 = __shfl(my, j0,     64); \
        unsigned b1 = __shfl(my, j0 + 2, 64); \
        unsigned b2 = __shfl(my, j0 + 4, 64); \
        unsigned b3 = __shfl(my, j0 + 6, 64); \
        if (jb + 8 <= degc) { ACCP(A, b0); ACCP(A, b1); ACCP(A, b2); ACCP(A, b3); } \
        else { \
            if (j0     < degc) ACCP(A, b0); \
            if (j0 + 2 < degc) ACCP(A, b1); \
            if (j0 + 4 < degc) ACCP(A, b2); \
            if (j0 + 6 < degc) ACCP(A, b3); } }

__global__ __launch_bounds__(256) void gather(
    const unsigned char* __restrict__ T8, const unsigned short* __restrict__ U,
    const int* __restrict__ offa, const int* __restrict__ dega,
    const unsigned* __restrict__ csr,
    const int* __restrict__ ocnt, const uint2* __restrict__ obuf,
    const float* __restrict__ nodes, const float* __restrict__ wse,
    float* __restrict__ outp)
{
    int wid = (blockIdx.x * 256 + threadIdx.x) >> 6;
    if (wid >= NNODES / 2) return;
    int n0 = wid * 2;
    int n1 = n0 + 1;
    int l = threadIdx.x & 63;
    int half = l >> 5;
    int c = l & 31;

    int deg0 = dega[n0];
    int deg1 = dega[n1];
    int beg0 = offa[n0];
    int beg1 = offa[n1];
    int degc0 = deg0 < 64 ? deg0 : 64;
    int degc1 = deg1 < 64 ? deg1 : 64;

    unsigned my0 = (l < degc0) ? csr[(size_t)beg0 + l] : 0u;
    unsigned my1 = (l < degc1) ? csr[(size_t)beg1 + l] : 0u;
    int nm = half ? n1 : n0;
    float4 spm = *(const float4*)(outp + (size_t)nm * DIM + c * 4);

    float4 acc0 = make_float4(0.f, 0.f, 0.f, 0.f);
    float4 acc1 = make_float4(0.f, 0.f, 0.f, 0.f);
    int maxd = degc0 > degc1 ? degc0 : degc1;
    for (int jb = 0; jb < maxd; jb += 8) {
        int j0 = jb + half;
        BATCH(my0, degc0, acc0);
        BATCH(my1, degc1, acc1);
    }

    // binned entries beyond 64 (~never; Poisson(12)) — loads only, safe
    for (int j = 64 + half; j < deg0; j += 2) ACCP(acc0, csr[(size_t)beg0 + j]);
    for (int j = 64 + half; j < deg1; j += 2) ACCP(acc1, csr[(size_t)beg1 + j]);

    // overflow drain (~never): count matches into the divisor too
    int dt0 = 0, dt1 = 0;
    int oc = *ocnt;
    if (oc > 0) {
        if (oc > OCAP) oc = OCAP;
        for (int k = 0; k < oc; ++k) {
            uint2 e = obuf[k];
            if ((int)e.x == n0) { dt0++; if ((k & 1) == half) ACCP(acc0, e.y); }
            if ((int)e.x == n1) { dt1++; if ((k & 1) == half) ACCP(acc1, e.y); }
        }
    }
    int degt0 = deg0 + dt0;
    int degt1 = deg1 + dt1;

    acc0.x += __shfl_xor(acc0.x, 32, 64);
    acc0.y += __shfl_xor(acc0.y, 32, 64);
    acc0.z += __shfl_xor(acc0.z, 32, 64);
    acc0.w += __shfl_xor(acc0.w, 32, 64);
    acc1.x += __shfl_xor(acc1.x, 32, 64);
    acc1.y += __shfl_xor(acc1.y, 32, 64);
    acc1.z += __shfl_xor(acc1.z, 32, 64);
    acc1.w += __shfl_xor(acc1.w, 32, 64);

    float4 am = half ? acc1 : acc0;
    int dm = half ? degt1 : degt0;
    if (dm > 0) {
        float inv = 1.0f / (float)dm;
        float4 o = { spm.x + am.x * inv, spm.y + am.y * inv,
                     spm.z + am.z * inv, spm.w + am.w * inv };
        *(float4*)(outp + (size_t)nm * DIM + c * 4) = o;
    }

    if (degt0 == 0 && half == 0) {
        float s0 = 0, s1 = 0, s2 = 0, s3 = 0;
        for (int k = 0; k < DIM; ++k) {
            float hk = nodes[(size_t)n0 * DIM + k];
            const float* wr = wse + (size_t)k * DIM + c * 4;
            s0 += hk * wr[0]; s1 += hk * wr[1];
            s2 += hk * wr[2]; s3 += hk * wr[3];
        }
        float4 hv = *(const float4*)(nodes + (size_t)n0 * DIM + c * 4);
        float4 o = { hv.x + s0, hv.y + s1, hv.z + s2, hv.w + s3 };
        *(float4*)(outp + (size_t)n0 * DIM + c * 4) = o;
    }
    if (degt1 == 0 && half == 1) {
        float s0 = 0, s1 = 0, s2 = 0, s3 = 0;
        for (int k = 0; k < DIM; ++k) {
            float hk = nodes[(size_t)n1 * DIM + k];
            const float* wr = wse + (size_t)k * DIM + c * 4;
            s0 += hk * wr[0]; s1 += hk * wr[1];
            s2 += hk * wr[2]; s3 += hk * wr[3];
        }
        float4 hv = *(const float4*)(nodes + (size_t)n1 * DIM + c * 4);
        float4 o = { hv.x + s0, hv.y + s1, hv.z + s2, hv.w + s3 };
        *(float4*)(outp + (size_t)n1 * DIM + c * 4) = o;
    }
}

// ---------------------------------------------------------------------------
extern "C" void kernel_launch(void* const* d_in, const int* in_sizes, int n_in,
                              void* d_out, int out_size, void* d_ws, size_t ws_size,
                              hipStream_t stream)
{
    const float* nodes = (const float*)d_in[0];
    const float* rels  = (const float*)d_in[1];
    const int*   edges = (const int*)d_in[2];
    const float* wn    = (const float*)d_in[3];
    const float* wsf   = (const float*)d_in[4];
    const float* wse   = (const float*)d_in[5];
    float* out = (float*)d_out;

    char* ws = (char*)d_ws;
    int*            gcur  = (int*)(ws + OFF_GCUR_B);
    int*            ocnt  = (int*)(ws + OFF_OCNT_B);
    uint2*          obuf  = (uint2*)(ws + OFF_OBUF_B);
    int*            offa  = (int*)(ws + OFF_OFFA_B);
    int*            dega  = (int*)(ws + OFF_DEGA_B);
    uint2*          ebin  = (uint2*)(ws + OFF_EBIN_B);
    unsigned*       csr   = (unsigned*)(ws + OFF_CSR_B);
    unsigned short* btn   = (unsigned short*)(ws + OFF_BTN_B);
    unsigned short* bts   = (unsigned short*)(ws + OFF_BTS_B);
    unsigned char*  T8    = (unsigned char*)(ws + OFF_T_B);
    unsigned short* U     = (unsigned short*)(ws + OFF_U_B);

    prep<<<PREP_BLKS, 256, 0, stream>>>(wn, wsf, btn, bts, (int4*)gcur);

    binA<<<ABLK, 256, 0, stream>>>(edges, gcur, ebin, ocnt, obuf);
    binB<<<NBIN, 256, 0, stream>>>(gcur, ebin, csr, offa, dega);

    ts_kernel<<<TS_BLKS, 256, 0, stream>>>(nodes, rels, btn, bts, T8, U, out);

    gather<<<GATHER_BLKS, 256, 0, stream>>>(T8, U, offa, dega, csr, ocnt, obuf,
                                            nodes, wse, out);
}

// Round 19
// 73.052 us; speedup vs baseline: 1.2995x; 1.0165x over previous
//
#include <hip/hip_runtime.h>

// URGCN layer, MI355X — round 19.
// r18 post-mortem: fp8-T worked (74.3us, absmax 0.14). This round:
// (1) fold binB into gather — one 1024-thread block per bin builds per-dst
//     lists in LDS (binB's work, now overlapped with gather's memory stalls),
//     each half-wave owns a node; kills binB kernel, csr buffer, offa/dega,
//     one launch gap, and ALL data-carrying shfls.
// (2) Sp stored bf16 (Spb) — saves ~26MB HBM traffic; out stays f32.
//
// Algebra: msg_agg = (Σ_e T[src] + u[rel]) / deg, T = h@Wn (fp8 store),
//          u = rel@Wn (bf16).  out = Spb + msg_agg, Spb = h@(I+Wself) (bf16).

constexpr int NNODES = 50000;
constexpr int NEDGES = 600000;
constexpr int NRELS  = 500;
constexpr int DIM    = 128;

constexpr int DPB    = 128;                        // dsts per bin
constexpr int NBIN   = (NNODES + DPB - 1) / DPB;   // 391
constexpr int BINCAP = 2048;                       // edges per bin (13 sigma)
constexpr int EPB_A  = 4096;                       // edges per binA block
constexpr int ABLK   = (NEDGES + EPB_A - 1) / EPB_A; // 147
constexpr int GSTR   = 16;                         // gcur stride (ints, 64B)
constexpr int OCAP   = 8192;
constexpr int LCAP   = 96;                         // LDS list cap per node

constexpr int NODE_BLKS = (NNODES + 63) / 64;   // 782
constexpr int REL_BLKS  = (NRELS  + 63) / 64;   // 8
constexpr int TS_BLKS   = NODE_BLKS + REL_BLKS; // 790

constexpr int BP = 136;   // LDS B row pitch (shorts)
constexpr int SP = 132;   // LDS f32 tile pitch (floats)

constexpr int WCONV_BLKS = (DIM * DIM + 255) / 256;   // 64
constexpr int ZERO_INT4S = 1604;                      // gcur + ocnt region
constexpr int ZERO_BLKS  = (ZERO_INT4S + 255) / 256;  // 7
constexpr int PREP_BLKS  = WCONV_BLKS + ZERO_BLKS;    // 71

// ---------------- workspace layout (bytes), ~25.9 MB ----------------
constexpr size_t OFF_GCUR_B = 0;          // int[NBIN*16] padded cursors
constexpr size_t OFF_OCNT_B = 25600;      // int
constexpr size_t OFF_OBUF_B = 25664;      // uint2[8192]
constexpr size_t OFF_EBIN_B = 91200;      // uint2[NBIN*BINCAP] 6.4MB
constexpr size_t OFF_BTN_B  = 6497344;    // ushort[128*128] Wn^T bf16
constexpr size_t OFF_BTS_B  = 6530112;    // ushort[128*128] (I+Ws)^T bf16
constexpr size_t OFF_T_B    = 6562880;    // uchar[50000*128] fp8 T (6.4MB)
constexpr size_t OFF_U_B    = 12962880;   // ushort[500*128] bf16 U
constexpr size_t OFF_SPB_B  = 13090880;   // ushort[50000*128] bf16 Sp (12.8MB)

typedef short s8f __attribute__((ext_vector_type(8)));   // 8 bf16
typedef float f4  __attribute__((ext_vector_type(4)));   // MFMA acc

static __device__ __forceinline__ unsigned short f2bf(float f) {
    unsigned u = __builtin_bit_cast(unsigned, f);
    u += 0x7FFFu + ((u >> 16) & 1u);
    return (unsigned short)(u >> 16);
}
static __device__ __forceinline__ float bflo(unsigned v) {
    return __builtin_bit_cast(float, v << 16);
}
static __device__ __forceinline__ float bfhi(unsigned v) {
    return __builtin_bit_cast(float, v & 0xFFFF0000u);
}

// ---- fp8 e4m3 pack/unpack (HW converts when available) ----
static __device__ __forceinline__ void dec_fp8x4(unsigned w, float* f) {
#if __has_builtin(__builtin_amdgcn_cvt_pk_f32_fp8)
    typedef float f2v __attribute__((ext_vector_type(2)));
    f2v lo = __builtin_amdgcn_cvt_pk_f32_fp8((int)w, false);
    f2v hi = __builtin_amdgcn_cvt_pk_f32_fp8((int)w, true);
    f[0] = lo[0]; f[1] = lo[1]; f[2] = hi[0]; f[3] = hi[1];
#else
    #pragma unroll
    for (int i = 0; i < 4; ++i) {
        unsigned b = (w >> (8 * i)) & 0xFFu;
        unsigned e = (b >> 3) & 15u, m = b & 7u;
        float v = e ? __builtin_bit_cast(float, ((e + 120u) << 23) | (m << 20))
                    : (float)m * 0.001953125f;
        f[i] = (b & 0x80u) ? -v : v;
    }
#endif
}
static __device__ __forceinline__ unsigned enc_fp8x4(float a, float b,
                                                     float cc, float d) {
#if __has_builtin(__builtin_amdgcn_cvt_pk_fp8_f32)
    int w = __builtin_amdgcn_cvt_pk_fp8_f32(a, b, 0, false);
    w = __builtin_amdgcn_cvt_pk_fp8_f32(cc, d, w, true);
    return (unsigned)w;
#else
    float vv[4] = {a, b, cc, d};
    unsigned w = 0;
    #pragma unroll
    for (int i = 0; i < 4; ++i) {
        unsigned u = __builtin_bit_cast(unsigned, vv[i]);
        unsigned s = u >> 31;
        unsigned au = u & 0x7FFFFFFFu;
        float af = __builtin_bit_cast(float, au);
        unsigned byte;
        if (af < 0.015625f) byte = s << 7;
        else {
            if (af > 448.f) au = 0x43E00000u;
            unsigned lsb = (au >> 20) & 1u;
            au += 0x7FFFFu + lsb;
            int e8 = (int)(au >> 23) - 120;
            unsigned m3 = (au >> 20) & 7u;
            if (e8 > 15) { e8 = 15; m3 = 6; }
            byte = (s << 7) | ((unsigned)e8 << 3) | m3;
        }
        w |= byte << (8 * i);
    }
    return w;
#endif
}

// ---------------------------------------------------------------------------
// prep: blocks [0,64) convert weights; blocks [64,71) zero gcur+ocnt.
__global__ __launch_bounds__(256) void prep(const float* __restrict__ wn,
                                            const float* __restrict__ wsf,
                                            unsigned short* __restrict__ btn,
                                            unsigned short* __restrict__ bts,
                                            int4* __restrict__ z4)
{
    int b = blockIdx.x;
    if (b < WCONV_BLKS) {
        int idx = b * 256 + threadIdx.x;
        int k = idx >> 7, j = idx & 127;
        btn[(size_t)j * DIM + k] = f2bf(wn[idx]);                         // Wn^T
        bts[(size_t)j * DIM + k] = f2bf(wsf[idx] + (k == j ? 1.f : 0.f)); // (I+Ws)^T
    } else {
        int idx = (b - WCONV_BLKS) * 256 + threadIdx.x;
        if (idx < ZERO_INT4S) z4[idx] = make_int4(0, 0, 0, 0);
    }
}

// ---------------------------------------------------------------------------
// binA: 4096 edges/block. LDS histogram over coarse bins, block scan, one
// global atomicAdd per (block,bin), staged bin-sorted writeout. (r17 form.)
// ---------------------------------------------------------------------------
__global__ __launch_bounds__(256) void binA(const int* __restrict__ edges,
                                            int* __restrict__ gcur,
                                            uint2* __restrict__ ebin,
                                            int* __restrict__ ocnt,
                                            uint2* __restrict__ obuf)
{
    __shared__ int hist[512];
    __shared__ int lpre[512];
    __shared__ int base[512];
    __shared__ uint2 stage[EPB_A];   // 32 KB
    __shared__ int   gdst[EPB_A];    // 16 KB

    int t  = threadIdx.x;
    int eb = blockIdx.x * EPB_A;

    hist[t] = 0; hist[t + 256] = 0;
    __syncthreads();

    int      bin_i[16];
    int      dst_i[16];
    unsigned pay_i[16];
    int      rnk_i[16];
    #pragma unroll
    for (int i = 0; i < 16; ++i) {
        int e = eb + i * 256 + t;
        bin_i[i] = -1;
        if (e < NEDGES) {
            int s = edges[3 * e], r = edges[3 * e + 1], d = edges[3 * e + 2];
            dst_i[i] = d;
            bin_i[i] = d >> 7;
            pay_i[i] = (unsigned)s | ((unsigned)r << 16);
            rnk_i[i] = atomicAdd(&hist[bin_i[i]], 1);
        }
    }
    __syncthreads();

    lpre[t] = hist[t]; lpre[t + 256] = hist[t + 256];
    __syncthreads();
    for (int d = 1; d < 512; d <<= 1) {
        int a0 = (t >= d) ? lpre[t - d] : 0;
        int a1 = lpre[t + 256 - d];
        __syncthreads();
        lpre[t] += a0; lpre[t + 256] += a1;
        __syncthreads();
    }

    if (t < NBIN && hist[t] > 0)
        base[t] = atomicAdd(gcur + (size_t)t * GSTR, hist[t]);
    if (t + 256 < NBIN && hist[t + 256] > 0)
        base[t + 256] = atomicAdd(gcur + (size_t)(t + 256) * GSTR, hist[t + 256]);
    __syncthreads();

    #pragma unroll
    for (int i = 0; i < 16; ++i) {
        if (bin_i[i] >= 0) {
            int b  = bin_i[i];
            int lp = (lpre[b] - hist[b]) + rnk_i[i];
            stage[lp] = make_uint2((unsigned)dst_i[i], pay_i[i]);
            int q = base[b] + rnk_i[i];
            gdst[lp] = (q < BINCAP) ? (b * BINCAP + q) : -1;
        }
    }
    __syncthreads();

    int ne = NEDGES - eb; if (ne > EPB_A) ne = EPB_A;
    for (int j = t; j < ne; j += 256) {
        int g = gdst[j];
        uint2 rec = stage[j];
        if (g >= 0) ebin[g] = rec;
        else { int o = atomicAdd(ocnt, 1); if (o < OCAP) obuf[o] = rec; }
    }
}

// ---------------------------------------------------------------------------
// ts_kernel: fused two-phase GEMM, ONE aliased LDS buffer, 4 blk/CU.
// Phase-1 packs fp8 (T) / bf16 (U); phase-2 packs bf16 Spb.
// ---------------------------------------------------------------------------
__global__ __launch_bounds__(256, 4) void ts_kernel(
    const float* __restrict__ nodes, const float* __restrict__ rels,
    const unsigned short* __restrict__ btn, const unsigned short* __restrict__ bts,
    unsigned char* __restrict__ T8, unsigned short* __restrict__ U,
    unsigned short* __restrict__ Spb)
{
    __shared__ __align__(16) char ldsRaw[DIM * BP * 2];   // 34816 B
    unsigned short* ldsB = (unsigned short*)ldsRaw;
    float*          ldsS = (float*)ldsRaw;                // aliased f32 tile

    int blk = blockIdx.x;
    bool isRel = blk >= NODE_BLKS;
    const float* A = isRel ? rels : nodes;
    int nrows = isRel ? NRELS : NNODES;
    int rowbase = (isRel ? (blk - NODE_BLKS) : blk) * 64;

    int t  = threadIdx.x;
    int wv = t >> 6;
    int l  = t & 63;
    int r0 = rowbase + wv * 16;
    int m  = l & 15;
    int kg = l >> 4;
    int arow  = r0 + m;
    int arowc = arow < nrows ? arow : nrows - 1;

    s8f afrag[4];
    #pragma unroll
    for (int ks = 0; ks < 4; ++ks) {
        const float* p = A + (size_t)arowc * DIM + ks * 32 + kg * 8;
        float4 x = *(const float4*)p;
        float4 y = *(const float4*)(p + 4);
        s8f a;
        a[0] = (short)f2bf(x.x); a[1] = (short)f2bf(x.y);
        a[2] = (short)f2bf(x.z); a[3] = (short)f2bf(x.w);
        a[4] = (short)f2bf(y.x); a[5] = (short)f2bf(y.y);
        a[6] = (short)f2bf(y.z); a[7] = (short)f2bf(y.w);
        afrag[ks] = a;
    }

    // phase 1: A @ Wn -> f32 LDS tile -> fp8 T / bf16 U
    #pragma unroll
    for (int i = 0; i < 8; ++i) {
        int idx = t + i * 256;
        int col = idx >> 4, slot = idx & 15;
        *(uint4*)(ldsB + (size_t)col * BP + slot * 8) =
            *(const uint4*)(btn + (size_t)col * DIM + slot * 8);
    }
    __syncthreads();

    f4 acc[8];
    #pragma unroll
    for (int ct = 0; ct < 8; ++ct) {
        int col = ct * 16 + m;
        const unsigned short* bp = ldsB + (size_t)col * BP + kg * 8;
        f4 a = {0.f, 0.f, 0.f, 0.f};
        #pragma unroll
        for (int ks = 0; ks < 4; ++ks)
            a = __builtin_amdgcn_mfma_f32_16x16x32_bf16(afrag[ks], *(const s8f*)(bp + ks * 32), a, 0, 0, 0);
        acc[ct] = a;
    }
    __syncthreads();

    #pragma unroll
    for (int ct = 0; ct < 8; ++ct)
        #pragma unroll
        for (int r = 0; r < 4; ++r)
            ldsS[((size_t)wv * 16 + kg * 4 + r) * SP + ct * 16 + m] = acc[ct][r];
    __syncthreads();

    #pragma unroll
    for (int p = 0; p < 4; ++p) {
        int row = p * 4 + kg;
        int rg  = r0 + row;
        if (rg < nrows) {
            const float* rp = &ldsS[((size_t)wv * 16 + row) * SP + m * 8];
            float4 x = *(const float4*)rp;
            float4 y = *(const float4*)(rp + 4);
            if (!isRel) {
                uint2 o = { enc_fp8x4(x.x, x.y, x.z, x.w),
                            enc_fp8x4(y.x, y.y, y.z, y.w) };
                *(uint2*)(T8 + (size_t)rg * DIM + m * 8) = o;
            } else {
                uint4 o;
                o.x = (unsigned)f2bf(x.x) | ((unsigned)f2bf(x.y) << 16);
                o.y = (unsigned)f2bf(x.z) | ((unsigned)f2bf(x.w) << 16);
                o.z = (unsigned)f2bf(y.x) | ((unsigned)f2bf(y.y) << 16);
                o.w = (unsigned)f2bf(y.z) | ((unsigned)f2bf(y.w) << 16);
                *(uint4*)(U + (size_t)rg * DIM + m * 8) = o;
            }
        }
    }
    if (isRel) return;

    __syncthreads();

    // phase 2: Spb = bf16( A @ (I+Ws) )
    #pragma unroll
    for (int i = 0; i < 8; ++i) {
        int idx = t + i * 256;
        int col = idx >> 4, slot = idx & 15;
        *(uint4*)(ldsB + (size_t)col * BP + slot * 8) =
            *(const uint4*)(bts + (size_t)col * DIM + slot * 8);
    }
    __syncthreads();

    #pragma unroll
    for (int ct = 0; ct < 8; ++ct) {
        int col = ct * 16 + m;
        const unsigned short* bp = ldsB + (size_t)col * BP + kg * 8;
        f4 a = {0.f, 0.f, 0.f, 0.f};
        #pragma unroll
        for (int ks = 0; ks < 4; ++ks)
            a = __builtin_amdgcn_mfma_f32_16x16x32_bf16(afrag[ks], *(const s8f*)(bp + ks * 32), a, 0, 0, 0);
        acc[ct] = a;
    }
    __syncthreads();

    #pragma unroll
    for (int ct = 0; ct < 8; ++ct)
        #pragma unroll
        for (int r = 0; r < 4; ++r)
            ldsS[((size_t)wv * 16 + kg * 4 + r) * SP + ct * 16 + m] = acc[ct][r];
    __syncthreads();

    #pragma unroll
    for (int p = 0; p < 4; ++p) {
        int row = p * 4 + kg;
        int rg  = r0 + row;
        if (rg < NNODES) {
            unsigned short* orow = Spb + (size_t)rg * DIM;
            #pragma unroll
            for (int j = 0; j < 2; ++j) {
                int c0 = m * 4 + j * 64;
                float4 s = *(const float4*)&ldsS[((size_t)wv * 16 + row) * SP + c0];
                uint2 o = { (unsigned)f2bf(s.x) | ((unsigned)f2bf(s.y) << 16),
                            (unsigned)f2bf(s.z) | ((unsigned)f2bf(s.w) << 16) };
                *(uint2*)(orow + c0) = o;
            }
        }
    }
}

// ---------------------------------------------------------------------------
// gatherbin: one 1024-thread block per bin. Stage per-dst payload lists in
// LDS (binB's work, overlapped with gather), then each HALF-WAVE owns one
// node: accumulate from its LDS list (broadcast reads, divergence-safe).
// deg>LCAP node: exact full-scan of the bin's ebin. obuf drained read-only.
// out = Spb + acc/deg (f32), deg==0 -> h + h@Wse fallback.
// ---------------------------------------------------------------------------
#define ACCE(e) { \
    unsigned tw = *(const unsigned*)(T8 + (size_t)((e) & 0xFFFFu) * DIM + c * 4); \
    uint2 uu = *(const uint2*)(U + (size_t)((e) >> 16) * DIM + c * 4); \
    float tf[4]; dec_fp8x4(tw, tf); \
    acc.x += tf[0] + bflo(uu.x); acc.y += tf[1] + bfhi(uu.x); \
    acc.z += tf[2] + bflo(uu.y); acc.w += tf[3] + bfhi(uu.y); }

__global__ __launch_bounds__(1024) void gatherbin(
    const unsigned char* __restrict__ T8, const unsigned short* __restrict__ U,
    const int* __restrict__ gcur, const uint2* __restrict__ ebin,
    const int* __restrict__ ocnt, const uint2* __restrict__ obuf,
    const unsigned short* __restrict__ Spb,
    const float* __restrict__ nodes, const float* __restrict__ wse,
    float* __restrict__ outp)
{
    __shared__ unsigned list[DPB * LCAP];   // 48 KB
    __shared__ int      cnt[DPB];

    int bin = blockIdx.x;
    int t   = threadIdx.x;
    int totraw = gcur[(size_t)bin * GSTR];
    int total  = totraw < BINCAP ? totraw : BINCAP;

    if (t < DPB) cnt[t] = 0;
    __syncthreads();

    for (int j = t; j < total; j += 1024) {
        uint2 rec = ebin[(size_t)bin * BINCAP + j];
        int dl = (int)(rec.x & (DPB - 1));
        int rk = atomicAdd(&cnt[dl], 1);
        if (rk < LCAP) list[dl * LCAP + rk] = rec.y;
    }
    __syncthreads();

    int wv = t >> 6;        // 0..15
    int l  = t & 63;
    int half = l >> 5;
    int c  = l & 31;

    int oc = *ocnt;
    if (oc > OCAP) oc = OCAP;

    #pragma unroll
    for (int r = 0; r < 4; ++r) {
        int dl = r * 32 + wv * 2 + half;
        int n  = bin * DPB + dl;
        if (n >= NNODES) continue;
        int degb = cnt[dl];
        float4 acc = make_float4(0.f, 0.f, 0.f, 0.f);

        if (degb <= LCAP) {
            const unsigned* lp = &list[dl * LCAP];
            int j = 0;
            for (; j + 3 < degb; j += 4) {
                unsigned e0 = lp[j], e1 = lp[j + 1];
                unsigned e2 = lp[j + 2], e3 = lp[j + 3];
                ACCE(e0); ACCE(e1); ACCE(e2); ACCE(e3);
            }
            for (; j < degb; ++j) { unsigned e0 = lp[j]; ACCE(e0); }
        } else {
            // ~impossible (P[deg>96] ~ 1e-50) but exact: rescan the bin
            for (int j = 0; j < total; ++j) {
                uint2 rec = ebin[(size_t)bin * BINCAP + j];
                if ((int)(rec.x & (DPB - 1)) == dl) { unsigned e0 = rec.y; ACCE(e0); }
            }
        }

        int dt = 0;
        for (int k = 0; k < oc; ++k) {          // oc ~ 0
            uint2 e2 = obuf[k];
            if ((int)e2.x == n) { dt++; unsigned e0 = e2.y; ACCE(e0); }
        }
        int deg = degb + dt;

        if (deg > 0) {
            uint2 sp = *(const uint2*)(Spb + (size_t)n * DIM + c * 4);
            float inv = 1.0f / (float)deg;
            float4 o = { bflo(sp.x) + acc.x * inv, bfhi(sp.x) + acc.y * inv,
                         bflo(sp.y) + acc.z * inv, bfhi(sp.y) + acc.w * inv };
            *(float4*)(outp + (size_t)n * DIM + c * 4) = o;
        } else {
            // rare (~6e-6 per node): out = h + h @ Wse
            float s0 = 0, s1 = 0, s2 = 0, s3 = 0;
            for (int k = 0; k < DIM; ++k) {
                float hk = nodes[(size_t)n * DIM + k];
                const float* wr = wse + (size_t)k * DIM + c * 4;
                s0 += hk * wr[0]; s1 += hk * wr[1];
                s2 += hk * wr[2]; s3 += hk * wr[3];
            }
            float4 hv = *(const float4*)(nodes + (size_t)n * DIM + c * 4);
            float4 o = { hv.x + s0, hv.y + s1, hv.z + s2, hv.w + s3 };
            *(float4*)(outp + (size_t)n * DIM + c * 4) = o;
        }
    }
}

// ---------------------------------------------------------------------------
extern "C" void kernel_launch(void* const* d_in, const int* in_sizes, int n_in,
                              void* d_out, int out_size, void* d_ws, size_t ws_size,
                              hipStream_t stream)
{
    const float* nodes = (const float*)d_in[0];
    const float* rels  = (const float*)d_in[1];
    const int*   edges = (const int*)d_in[2];
    const float* wn    = (const float*)d_in[3];
    const float* wsf   = (const float*)d_in[4];
    const float* wse   = (const float*)d_in[5];
    float* out = (float*)d_out;

    char* ws = (char*)d_ws;
    int*            gcur  = (int*)(ws + OFF_GCUR_B);
    int*            ocnt  = (int*)(ws + OFF_OCNT_B);
    uint2*          obuf  = (uint2*)(ws + OFF_OBUF_B);
    uint2*          ebin  = (uint2*)(ws + OFF_EBIN_B);
    unsigned short* btn   = (unsigned short*)(ws + OFF_BTN_B);
    unsigned short* bts   = (unsigned short*)(ws + OFF_BTS_B);
    unsigned char*  T8    = (unsigned char*)(ws + OFF_T_B);
    unsigned short* U     = (unsigned short*)(ws + OFF_U_B);
    unsigned short* Spb   = (unsigned short*)(ws + OFF_SPB_B);

    prep<<<PREP_BLKS, 256, 0, stream>>>(wn, wsf, btn, bts, (int4*)gcur);

    binA<<<ABLK, 256, 0, stream>>>(edges, gcur, ebin, ocnt, obuf);

    ts_kernel<<<TS_BLKS, 256, 0, stream>>>(nodes, rels, btn, bts, T8, U, Spb);

    gatherbin<<<NBIN, 1024, 0, stream>>>(T8, U, gcur, ebin, ocnt, obuf, Spb,
                                         nodes, wse, out);
}

// Round 20
// 62.045 us; speedup vs baseline: 1.5300x; 1.1774x over previous
//
#include <hip/hip_runtime.h>

// URGCN layer, MI355X — round 20.
// r19 post-mortem: ~33us gatherbin (cache-throughput floor for the random
// T/U row stream), binA 7 + ts 11 + prep 2 + ~8us of launch gaps. This
// round: fuse binA INTO ts (role-dispatched blocks, binA-role first so it
// hides under ts). binA's LDS shrunk 54->38.9KB by packing (dst|q<<16) into
// the stage record (gdst array eliminated) -> union LDS 38.9KB keeps 4
// blocks/CU for both roles. One fewer launch; binA runs concurrent with ts.
//
// Algebra: msg_agg = (Σ_e T[src] + u[rel]) / deg, T = h@Wn (fp8 store),
//          u = rel@Wn (bf16).  out = Spb + msg_agg, Spb = h@(I+Wself) (bf16).

constexpr int NNODES = 50000;
constexpr int NEDGES = 600000;
constexpr int NRELS  = 500;
constexpr int DIM    = 128;

constexpr int DPB    = 128;                        // dsts per bin
constexpr int NBIN   = (NNODES + DPB - 1) / DPB;   // 391
constexpr int BINCAP = 2048;                       // edges per bin (13 sigma)
constexpr int EPB_A  = 4096;                       // edges per binA block
constexpr int ABLK   = (NEDGES + EPB_A - 1) / EPB_A; // 147
constexpr int GSTR   = 16;                         // gcur stride (ints, 64B)
constexpr int OCAP   = 8192;
constexpr int LCAP   = 96;                         // LDS list cap per node

constexpr int NODE_BLKS = (NNODES + 63) / 64;   // 782
constexpr int REL_BLKS  = (NRELS  + 63) / 64;   // 8
constexpr int TS_BLKS   = NODE_BLKS + REL_BLKS; // 790
constexpr int BATS_BLKS = ABLK + TS_BLKS;       // 937 (binA role first)

constexpr int BP = 136;   // LDS B row pitch (shorts)
constexpr int SP = 132;   // LDS f32 tile pitch (floats)

constexpr int WCONV_BLKS = (DIM * DIM + 255) / 256;   // 64
constexpr int ZERO_INT4S = 1604;                      // gcur + ocnt region
constexpr int ZERO_BLKS  = (ZERO_INT4S + 255) / 256;  // 7
constexpr int PREP_BLKS  = WCONV_BLKS + ZERO_BLKS;    // 71

// ---------------- workspace layout (bytes) ----------------
constexpr size_t OFF_GCUR_B = 0;          // int[NBIN*16] padded cursors
constexpr size_t OFF_OCNT_B = 25600;      // int
constexpr size_t OFF_OBUF_B = 25664;      // uint2[8192]
constexpr size_t OFF_EBIN_B = 91200;      // uint2[NBIN*BINCAP] 6.4MB
constexpr size_t OFF_BTN_B  = 6497344;    // ushort[128*128] Wn^T bf16
constexpr size_t OFF_BTS_B  = 6530112;    // ushort[128*128] (I+Ws)^T bf16
constexpr size_t OFF_T_B    = 6562880;    // uchar[50000*128] fp8 T (6.4MB)
constexpr size_t OFF_U_B    = 12962880;   // ushort[500*128] bf16 U
constexpr size_t OFF_SPB_B  = 13090880;   // ushort[50000*128] bf16 Sp (12.8MB)

typedef short s8f __attribute__((ext_vector_type(8)));   // 8 bf16
typedef float f4  __attribute__((ext_vector_type(4)));   // MFMA acc

static __device__ __forceinline__ unsigned short f2bf(float f) {
    unsigned u = __builtin_bit_cast(unsigned, f);
    u += 0x7FFFu + ((u >> 16) & 1u);
    return (unsigned short)(u >> 16);
}
static __device__ __forceinline__ float bflo(unsigned v) {
    return __builtin_bit_cast(float, v << 16);
}
static __device__ __forceinline__ float bfhi(unsigned v) {
    return __builtin_bit_cast(float, v & 0xFFFF0000u);
}

// ---- fp8 e4m3 pack/unpack (HW converts when available) ----
static __device__ __forceinline__ void dec_fp8x4(unsigned w, float* f) {
#if __has_builtin(__builtin_amdgcn_cvt_pk_f32_fp8)
    typedef float f2v __attribute__((ext_vector_type(2)));
    f2v lo = __builtin_amdgcn_cvt_pk_f32_fp8((int)w, false);
    f2v hi = __builtin_amdgcn_cvt_pk_f32_fp8((int)w, true);
    f[0] = lo[0]; f[1] = lo[1]; f[2] = hi[0]; f[3] = hi[1];
#else
    #pragma unroll
    for (int i = 0; i < 4; ++i) {
        unsigned b = (w >> (8 * i)) & 0xFFu;
        unsigned e = (b >> 3) & 15u, m = b & 7u;
        float v = e ? __builtin_bit_cast(float, ((e + 120u) << 23) | (m << 20))
                    : (float)m * 0.001953125f;
        f[i] = (b & 0x80u) ? -v : v;
    }
#endif
}
static __device__ __forceinline__ unsigned enc_fp8x4(float a, float b,
                                                     float cc, float d) {
#if __has_builtin(__builtin_amdgcn_cvt_pk_fp8_f32)
    int w = __builtin_amdgcn_cvt_pk_fp8_f32(a, b, 0, false);
    w = __builtin_amdgcn_cvt_pk_fp8_f32(cc, d, w, true);
    return (unsigned)w;
#else
    float vv[4] = {a, b, cc, d};
    unsigned w = 0;
    #pragma unroll
    for (int i = 0; i < 4; ++i) {
        unsigned u = __builtin_bit_cast(unsigned, vv[i]);
        unsigned s = u >> 31;
        unsigned au = u & 0x7FFFFFFFu;
        float af = __builtin_bit_cast(float, au);
        unsigned byte;
        if (af < 0.015625f) byte = s << 7;
        else {
            if (af > 448.f) au = 0x43E00000u;
            unsigned lsb = (au >> 20) & 1u;
            au += 0x7FFFFu + lsb;
            int e8 = (int)(au >> 23) - 120;
            unsigned m3 = (au >> 20) & 7u;
            if (e8 > 15) { e8 = 15; m3 = 6; }
            byte = (s << 7) | ((unsigned)e8 << 3) | m3;
        }
        w |= byte << (8 * i);
    }
    return w;
#endif
}

// ---------------------------------------------------------------------------
// prep: blocks [0,64) convert weights; blocks [64,71) zero gcur+ocnt.
__global__ __launch_bounds__(256) void prep(const float* __restrict__ wn,
                                            const float* __restrict__ wsf,
                                            unsigned short* __restrict__ btn,
                                            unsigned short* __restrict__ bts,
                                            int4* __restrict__ z4)
{
    int b = blockIdx.x;
    if (b < WCONV_BLKS) {
        int idx = b * 256 + threadIdx.x;
        int k = idx >> 7, j = idx & 127;
        btn[(size_t)j * DIM + k] = f2bf(wn[idx]);                         // Wn^T
        bts[(size_t)j * DIM + k] = f2bf(wsf[idx] + (k == j ? 1.f : 0.f)); // (I+Ws)^T
    } else {
        int idx = (b - WCONV_BLKS) * 256 + threadIdx.x;
        if (idx < ZERO_INT4S) z4[idx] = make_int4(0, 0, 0, 0);
    }
}

// ---------------------------------------------------------------------------
// bats: fused binA + ts, role-dispatched. Blocks [0,ABLK) run binA (edge
// binning, 38.9KB LDS incl. packed stage); blocks [ABLK,..) run the two-phase
// GEMM (34.8KB). Union LDS 38.9KB -> 4 blocks/CU for both roles.
// ---------------------------------------------------------------------------
__global__ __launch_bounds__(256, 4) void bats(
    const int* __restrict__ edges,
    int* __restrict__ gcur, uint2* __restrict__ ebin,
    int* __restrict__ ocnt, uint2* __restrict__ obuf,
    const float* __restrict__ nodes, const float* __restrict__ rels,
    const unsigned short* __restrict__ btn, const unsigned short* __restrict__ bts,
    unsigned char* __restrict__ T8, unsigned short* __restrict__ U,
    unsigned short* __restrict__ Spb)
{
    __shared__ __align__(16) char ldsRaw[6144 + EPB_A * 8];   // 38912 B
    int bid = blockIdx.x;
    int t   = threadIdx.x;

    if (bid < ABLK) {
        // ================= binA role =================
        int*   hist  = (int*)ldsRaw;                 // [512]
        int*   lpre  = (int*)(ldsRaw + 2048);        // [512]
        int*   base  = (int*)(ldsRaw + 4096);        // [512]
        uint2* stage = (uint2*)(ldsRaw + 6144);      // [4096]

        int eb = bid * EPB_A;
        hist[t] = 0; hist[t + 256] = 0;
        __syncthreads();

        int      bin_i[16];
        int      dst_i[16];
        unsigned pay_i[16];
        int      rnk_i[16];
        #pragma unroll
        for (int i = 0; i < 16; ++i) {
            int e = eb + i * 256 + t;
            bin_i[i] = -1;
            if (e < NEDGES) {
                int s = edges[3 * e], r = edges[3 * e + 1], d = edges[3 * e + 2];
                dst_i[i] = d;
                bin_i[i] = d >> 7;
                pay_i[i] = (unsigned)s | ((unsigned)r << 16);
                rnk_i[i] = atomicAdd(&hist[bin_i[i]], 1);
            }
        }
        __syncthreads();

        lpre[t] = hist[t]; lpre[t + 256] = hist[t + 256];
        __syncthreads();
        for (int d = 1; d < 512; d <<= 1) {
            int a0 = (t >= d) ? lpre[t - d] : 0;
            int a1 = lpre[t + 256 - d];
            __syncthreads();
            lpre[t] += a0; lpre[t + 256] += a1;
            __syncthreads();
        }

        if (t < NBIN && hist[t] > 0)
            base[t] = atomicAdd(gcur + (size_t)t * GSTR, hist[t]);
        if (t + 256 < NBIN && hist[t + 256] > 0)
            base[t + 256] = atomicAdd(gcur + (size_t)(t + 256) * GSTR, hist[t + 256]);
        __syncthreads();

        // stage: x = dst | min(q,0xFFFF)<<16 ; y = payload
        #pragma unroll
        for (int i = 0; i < 16; ++i) {
            if (bin_i[i] >= 0) {
                int b  = bin_i[i];
                int lp = (lpre[b] - hist[b]) + rnk_i[i];
                int q  = base[b] + rnk_i[i];
                unsigned qc = q < 0xFFFF ? (unsigned)q : 0xFFFFu;
                stage[lp] = make_uint2((unsigned)dst_i[i] | (qc << 16), pay_i[i]);
            }
        }
        __syncthreads();

        int ne = NEDGES - eb; if (ne > EPB_A) ne = EPB_A;
        for (int j = t; j < ne; j += 256) {
            uint2 rec = stage[j];
            unsigned dst = rec.x & 0xFFFFu;
            unsigned q   = rec.x >> 16;
            if (q < BINCAP)
                ebin[(size_t)(dst >> 7) * BINCAP + q] = make_uint2(dst, rec.y);
            else {
                int o = atomicAdd(ocnt, 1);
                if (o < OCAP) obuf[o] = make_uint2(dst, rec.y);
            }
        }
        return;
    }

    // ================= ts role =================
    unsigned short* ldsB = (unsigned short*)ldsRaw;
    float*          ldsS = (float*)ldsRaw;

    int blk = bid - ABLK;
    bool isRel = blk >= NODE_BLKS;
    const float* A = isRel ? rels : nodes;
    int nrows = isRel ? NRELS : NNODES;
    int rowbase = (isRel ? (blk - NODE_BLKS) : blk) * 64;

    int wv = t >> 6;
    int l  = t & 63;
    int r0 = rowbase + wv * 16;
    int m  = l & 15;
    int kg = l >> 4;
    int arow  = r0 + m;
    int arowc = arow < nrows ? arow : nrows - 1;

    s8f afrag[4];
    #pragma unroll
    for (int ks = 0; ks < 4; ++ks) {
        const float* p = A + (size_t)arowc * DIM + ks * 32 + kg * 8;
        float4 x = *(const float4*)p;
        float4 y = *(const float4*)(p + 4);
        s8f a;
        a[0] = (short)f2bf(x.x); a[1] = (short)f2bf(x.y);
        a[2] = (short)f2bf(x.z); a[3] = (short)f2bf(x.w);
        a[4] = (short)f2bf(y.x); a[5] = (short)f2bf(y.y);
        a[6] = (short)f2bf(y.z); a[7] = (short)f2bf(y.w);
        afrag[ks] = a;
    }

    // phase 1: A @ Wn -> f32 LDS tile -> fp8 T / bf16 U
    #pragma unroll
    for (int i = 0; i < 8; ++i) {
        int idx = t + i * 256;
        int col = idx >> 4, slot = idx & 15;
        *(uint4*)(ldsB + (size_t)col * BP + slot * 8) =
            *(const uint4*)(btn + (size_t)col * DIM + slot * 8);
    }
    __syncthreads();

    f4 acc[8];
    #pragma unroll
    for (int ct = 0; ct < 8; ++ct) {
        int col = ct * 16 + m;
        const unsigned short* bp = ldsB + (size_t)col * BP + kg * 8;
        f4 a = {0.f, 0.f, 0.f, 0.f};
        #pragma unroll
        for (int ks = 0; ks < 4; ++ks)
            a = __builtin_amdgcn_mfma_f32_16x16x32_bf16(afrag[ks], *(const s8f*)(bp + ks * 32), a, 0, 0, 0);
        acc[ct] = a;
    }
    __syncthreads();

    #pragma unroll
    for (int ct = 0; ct < 8; ++ct)
        #pragma unroll
        for (int r = 0; r < 4; ++r)
            ldsS[((size_t)wv * 16 + kg * 4 + r) * SP + ct * 16 + m] = acc[ct][r];
    __syncthreads();

    #pragma unroll
    for (int p = 0; p < 4; ++p) {
        int row = p * 4 + kg;
        int rg  = r0 + row;
        if (rg < nrows) {
            const float* rp = &ldsS[((size_t)wv * 16 + row) * SP + m * 8];
            float4 x = *(const float4*)rp;
            float4 y = *(const float4*)(rp + 4);
            if (!isRel) {
                uint2 o = { enc_fp8x4(x.x, x.y, x.z, x.w),
                            enc_fp8x4(y.x, y.y, y.z, y.w) };
                *(uint2*)(T8 + (size_t)rg * DIM + m * 8) = o;
            } else {
                uint4 o;
                o.x = (unsigned)f2bf(x.x) | ((unsigned)f2bf(x.y) << 16);
                o.y = (unsigned)f2bf(x.z) | ((unsigned)f2bf(x.w) << 16);
                o.z = (unsigned)f2bf(y.x) | ((unsigned)f2bf(y.y) << 16);
                o.w = (unsigned)f2bf(y.z) | ((unsigned)f2bf(y.w) << 16);
                *(uint4*)(U + (size_t)rg * DIM + m * 8) = o;
            }
        }
    }
    if (isRel) return;

    __syncthreads();

    // phase 2: Spb = bf16( A @ (I+Ws) )
    #pragma unroll
    for (int i = 0; i < 8; ++i) {
        int idx = t + i * 256;
        int col = idx >> 4, slot = idx & 15;
        *(uint4*)(ldsB + (size_t)col * BP + slot * 8) =
            *(const uint4*)(bts + (size_t)col * DIM + slot * 8);
    }
    __syncthreads();

    #pragma unroll
    for (int ct = 0; ct < 8; ++ct) {
        int col = ct * 16 + m;
        const unsigned short* bp = ldsB + (size_t)col * BP + kg * 8;
        f4 a = {0.f, 0.f, 0.f, 0.f};
        #pragma unroll
        for (int ks = 0; ks < 4; ++ks)
            a = __builtin_amdgcn_mfma_f32_16x16x32_bf16(afrag[ks], *(const s8f*)(bp + ks * 32), a, 0, 0, 0);
        acc[ct] = a;
    }
    __syncthreads();

    #pragma unroll
    for (int ct = 0; ct < 8; ++ct)
        #pragma unroll
        for (int r = 0; r < 4; ++r)
            ldsS[((size_t)wv * 16 + kg * 4 + r) * SP + ct * 16 + m] = acc[ct][r];
    __syncthreads();

    #pragma unroll
    for (int p = 0; p < 4; ++p) {
        int row = p * 4 + kg;
        int rg  = r0 + row;
        if (rg < NNODES) {
            unsigned short* orow = Spb + (size_t)rg * DIM;
            #pragma unroll
            for (int j = 0; j < 2; ++j) {
                int c0 = m * 4 + j * 64;
                float4 s = *(const float4*)&ldsS[((size_t)wv * 16 + row) * SP + c0];
                uint2 o = { (unsigned)f2bf(s.x) | ((unsigned)f2bf(s.y) << 16),
                            (unsigned)f2bf(s.z) | ((unsigned)f2bf(s.w) << 16) };
                *(uint2*)(orow + c0) = o;
            }
        }
    }
}

// ---------------------------------------------------------------------------
// gatherbin: one 1024-thread block per bin (r19 form, sp-load hoisted).
// ---------------------------------------------------------------------------
#define ACCE(e) { \
    unsigned tw = *(const unsigned*)(T8 + (size_t)((e) & 0xFFFFu) * DIM + c * 4); \
    uint2 uu = *(const uint2*)(U + (size_t)((e) >> 16) * DIM + c * 4); \
    float tf[4]; dec_fp8x4(tw, tf); \
    acc.x += tf[0] + bflo(uu.x); acc.y += tf[1] + bfhi(uu.x); \
    acc.z += tf[2] + bflo(uu.y); acc.w += tf[3] + bfhi(uu.y); }

__global__ __launch_bounds__(1024) void gatherbin(
    const unsigned char* __restrict__ T8, const unsigned short* __restrict__ U,
    const int* __restrict__ gcur, const uint2* __restrict__ ebin,
    const int* __restrict__ ocnt, const uint2* __restrict__ obuf,
    const unsigned short* __restrict__ Spb,
    const float* __restrict__ nodes, const float* __restrict__ wse,
    float* __restrict__ outp)
{
    __shared__ unsigned list[DPB * LCAP];   // 48 KB
    __shared__ int      cnt[DPB];

    int bin = blockIdx.x;
    int t   = threadIdx.x;
    int totraw = gcur[(size_t)bin * GSTR];
    int total  = totraw < BINCAP ? totraw : BINCAP;

    if (t < DPB) cnt[t] = 0;
    __syncthreads();

    for (int j = t; j < total; j += 1024) {
        uint2 rec = ebin[(size_t)bin * BINCAP + j];
        int dl = (int)(rec.x & (DPB - 1));
        int rk = atomicAdd(&cnt[dl], 1);
        if (rk < LCAP) list[dl * LCAP + rk] = rec.y;
    }
    __syncthreads();

    int wv = t >> 6;        // 0..15
    int l  = t & 63;
    int half = l >> 5;
    int c  = l & 31;

    int oc = *ocnt;
    if (oc > OCAP) oc = OCAP;

    #pragma unroll
    for (int r = 0; r < 4; ++r) {
        int dl = r * 32 + wv * 2 + half;
        int n  = bin * DPB + dl;
        if (n >= NNODES) continue;
        int degb = cnt[dl];
        uint2 sp = *(const uint2*)(Spb + (size_t)n * DIM + c * 4);  // hoisted
        float4 acc = make_float4(0.f, 0.f, 0.f, 0.f);

        if (degb <= LCAP) {
            const unsigned* lp = &list[dl * LCAP];
            int j = 0;
            for (; j + 3 < degb; j += 4) {
                unsigned e0 = lp[j], e1 = lp[j + 1];
                unsigned e2 = lp[j + 2], e3 = lp[j + 3];
                ACCE(e0); ACCE(e1); ACCE(e2); ACCE(e3);
            }
            for (; j < degb; ++j) { unsigned e0 = lp[j]; ACCE(e0); }
        } else {
            for (int j = 0; j < total; ++j) {
                uint2 rec = ebin[(size_t)bin * BINCAP + j];
                if ((int)(rec.x & (DPB - 1)) == dl) { unsigned e0 = rec.y; ACCE(e0); }
            }
        }

        int dt = 0;
        for (int k = 0; k < oc; ++k) {          // oc ~ 0
            uint2 e2 = obuf[k];
            if ((int)e2.x == n) { dt++; unsigned e0 = e2.y; ACCE(e0); }
        }
        int deg = degb + dt;

        if (deg > 0) {
            float inv = 1.0f / (float)deg;
            float4 o = { bflo(sp.x) + acc.x * inv, bfhi(sp.x) + acc.y * inv,
                         bflo(sp.y) + acc.z * inv, bfhi(sp.y) + acc.w * inv };
            *(float4*)(outp + (size_t)n * DIM + c * 4) = o;
        } else {
            // rare (~6e-6 per node): out = h + h @ Wse
            float s0 = 0, s1 = 0, s2 = 0, s3 = 0;
            for (int k = 0; k < DIM; ++k) {
                float hk = nodes[(size_t)n * DIM + k];
                const float* wr = wse + (size_t)k * DIM + c * 4;
                s0 += hk * wr[0]; s1 += hk * wr[1];
                s2 += hk * wr[2]; s3 += hk * wr[3];
            }
            float4 hv = *(const float4*)(nodes + (size_t)n * DIM + c * 4);
            float4 o = { hv.x + s0, hv.y + s1, hv.z + s2, hv.w + s3 };
            *(float4*)(outp + (size_t)n * DIM + c * 4) = o;
        }
    }
}

// ---------------------------------------------------------------------------
extern "C" void kernel_launch(void* const* d_in, const int* in_sizes, int n_in,
                              void* d_out, int out_size, void* d_ws, size_t ws_size,
                              hipStream_t stream)
{
    const float* nodes = (const float*)d_in[0];
    const float* rels  = (const float*)d_in[1];
    const int*   edges = (const int*)d_in[2];
    const float* wn    = (const float*)d_in[3];
    const float* wsf   = (const float*)d_in[4];
    const float* wse   = (const float*)d_in[5];
    float* out = (float*)d_out;

    char* ws = (char*)d_ws;
    int*            gcur  = (int*)(ws + OFF_GCUR_B);
    int*            ocnt  = (int*)(ws + OFF_OCNT_B);
    uint2*          obuf  = (uint2*)(ws + OFF_OBUF_B);
    uint2*          ebin  = (uint2*)(ws + OFF_EBIN_B);
    unsigned short* btn   = (unsigned short*)(ws + OFF_BTN_B);
    unsigned short* bts   = (unsigned short*)(ws + OFF_BTS_B);
    unsigned char*  T8    = (unsigned char*)(ws + OFF_T_B);
    unsigned short* U     = (unsigned short*)(ws + OFF_U_B);
    unsigned short* Spb   = (unsigned short*)(ws + OFF_SPB_B);

    prep<<<PREP_BLKS, 256, 0, stream>>>(wn, wsf, btn, bts, (int4*)gcur);

    bats<<<BATS_BLKS, 256, 0, stream>>>(edges, gcur, ebin, ocnt, obuf,
                                        nodes, rels, btn, bts, T8, U, Spb);

    gatherbin<<<NBIN, 1024, 0, stream>>>(T8, U, gcur, ebin, ocnt, obuf, Spb,
                                         nodes, wse, out);
}

// Round 21
// 61.821 us; speedup vs baseline: 1.5356x; 1.0036x over previous
//
#include <hip/hip_runtime.h>

// URGCN layer, MI355X — round 21.
// r20 post-mortem: bats fusion worked (62us). gatherbin (~33us) suffers ~24%
// load-imbalance tail (391 blocks on 512 slots). Fix: half-bin gather blocks
// — 782 x 256-thread blocks, each stages its 64 dsts from the parent bin's
// ebin segment (2x sequential scan, +1us) -> 6 blocks/CU, tail ~9%.
// binA reservation granularity unchanged (57k atomics).
//
// Algebra: msg_agg = (Σ_e T[src] + u[rel]) / deg, T = h@Wn (fp8 store),
//          u = rel@Wn (bf16).  out = Spb + msg_agg, Spb = h@(I+Wself) (bf16).

constexpr int NNODES = 50000;
constexpr int NEDGES = 600000;
constexpr int NRELS  = 500;
constexpr int DIM    = 128;

constexpr int DPB    = 128;                        // dsts per bin
constexpr int NBIN   = (NNODES + DPB - 1) / DPB;   // 391
constexpr int BINCAP = 2048;                       // edges per bin (13 sigma)
constexpr int EPB_A  = 4096;                       // edges per binA block
constexpr int ABLK   = (NEDGES + EPB_A - 1) / EPB_A; // 147
constexpr int GSTR   = 16;                         // gcur stride (ints, 64B)
constexpr int OCAP   = 8192;
constexpr int LCAP   = 96;                         // LDS list cap per node

constexpr int NODE_BLKS = (NNODES + 63) / 64;   // 782
constexpr int REL_BLKS  = (NRELS  + 63) / 64;   // 8
constexpr int TS_BLKS   = NODE_BLKS + REL_BLKS; // 790
constexpr int BATS_BLKS = ABLK + TS_BLKS;       // 937 (binA role first)

constexpr int BP = 136;   // LDS B row pitch (shorts)
constexpr int SP = 132;   // LDS f32 tile pitch (floats)

constexpr int WCONV_BLKS = (DIM * DIM + 255) / 256;   // 64
constexpr int ZERO_INT4S = 1604;                      // gcur + ocnt region
constexpr int ZERO_BLKS  = (ZERO_INT4S + 255) / 256;  // 7
constexpr int PREP_BLKS  = WCONV_BLKS + ZERO_BLKS;    // 71

constexpr int GB_BLKS = NBIN * 2;                     // 782 half-bin blocks

// ---------------- workspace layout (bytes) ----------------
constexpr size_t OFF_GCUR_B = 0;          // int[NBIN*16] padded cursors
constexpr size_t OFF_OCNT_B = 25600;      // int
constexpr size_t OFF_OBUF_B = 25664;      // uint2[8192]
constexpr size_t OFF_EBIN_B = 91200;      // uint2[NBIN*BINCAP] 6.4MB
constexpr size_t OFF_BTN_B  = 6497344;    // ushort[128*128] Wn^T bf16
constexpr size_t OFF_BTS_B  = 6530112;    // ushort[128*128] (I+Ws)^T bf16
constexpr size_t OFF_T_B    = 6562880;    // uchar[50000*128] fp8 T (6.4MB)
constexpr size_t OFF_U_B    = 12962880;   // ushort[500*128] bf16 U
constexpr size_t OFF_SPB_B  = 13090880;   // ushort[50000*128] bf16 Sp (12.8MB)

typedef short s8f __attribute__((ext_vector_type(8)));   // 8 bf16
typedef float f4  __attribute__((ext_vector_type(4)));   // MFMA acc

static __device__ __forceinline__ unsigned short f2bf(float f) {
    unsigned u = __builtin_bit_cast(unsigned, f);
    u += 0x7FFFu + ((u >> 16) & 1u);
    return (unsigned short)(u >> 16);
}
static __device__ __forceinline__ float bflo(unsigned v) {
    return __builtin_bit_cast(float, v << 16);
}
static __device__ __forceinline__ float bfhi(unsigned v) {
    return __builtin_bit_cast(float, v & 0xFFFF0000u);
}

// ---- fp8 e4m3 pack/unpack (HW converts when available) ----
static __device__ __forceinline__ void dec_fp8x4(unsigned w, float* f) {
#if __has_builtin(__builtin_amdgcn_cvt_pk_f32_fp8)
    typedef float f2v __attribute__((ext_vector_type(2)));
    f2v lo = __builtin_amdgcn_cvt_pk_f32_fp8((int)w, false);
    f2v hi = __builtin_amdgcn_cvt_pk_f32_fp8((int)w, true);
    f[0] = lo[0]; f[1] = lo[1]; f[2] = hi[0]; f[3] = hi[1];
#else
    #pragma unroll
    for (int i = 0; i < 4; ++i) {
        unsigned b = (w >> (8 * i)) & 0xFFu;
        unsigned e = (b >> 3) & 15u, m = b & 7u;
        float v = e ? __builtin_bit_cast(float, ((e + 120u) << 23) | (m << 20))
                    : (float)m * 0.001953125f;
        f[i] = (b & 0x80u) ? -v : v;
    }
#endif
}
static __device__ __forceinline__ unsigned enc_fp8x4(float a, float b,
                                                     float cc, float d) {
#if __has_builtin(__builtin_amdgcn_cvt_pk_fp8_f32)
    int w = __builtin_amdgcn_cvt_pk_fp8_f32(a, b, 0, false);
    w = __builtin_amdgcn_cvt_pk_fp8_f32(cc, d, w, true);
    return (unsigned)w;
#else
    float vv[4] = {a, b, cc, d};
    unsigned w = 0;
    #pragma unroll
    for (int i = 0; i < 4; ++i) {
        unsigned u = __builtin_bit_cast(unsigned, vv[i]);
        unsigned s = u >> 31;
        unsigned au = u & 0x7FFFFFFFu;
        float af = __builtin_bit_cast(float, au);
        unsigned byte;
        if (af < 0.015625f) byte = s << 7;
        else {
            if (af > 448.f) au = 0x43E00000u;
            unsigned lsb = (au >> 20) & 1u;
            au += 0x7FFFFu + lsb;
            int e8 = (int)(au >> 23) - 120;
            unsigned m3 = (au >> 20) & 7u;
            if (e8 > 15) { e8 = 15; m3 = 6; }
            byte = (s << 7) | ((unsigned)e8 << 3) | m3;
        }
        w |= byte << (8 * i);
    }
    return w;
#endif
}

// ---------------------------------------------------------------------------
// prep: blocks [0,64) convert weights; blocks [64,71) zero gcur+ocnt.
__global__ __launch_bounds__(256) void prep(const float* __restrict__ wn,
                                            const float* __restrict__ wsf,
                                            unsigned short* __restrict__ btn,
                                            unsigned short* __restrict__ bts,
                                            int4* __restrict__ z4)
{
    int b = blockIdx.x;
    if (b < WCONV_BLKS) {
        int idx = b * 256 + threadIdx.x;
        int k = idx >> 7, j = idx & 127;
        btn[(size_t)j * DIM + k] = f2bf(wn[idx]);                         // Wn^T
        bts[(size_t)j * DIM + k] = f2bf(wsf[idx] + (k == j ? 1.f : 0.f)); // (I+Ws)^T
    } else {
        int idx = (b - WCONV_BLKS) * 256 + threadIdx.x;
        if (idx < ZERO_INT4S) z4[idx] = make_int4(0, 0, 0, 0);
    }
}

// ---------------------------------------------------------------------------
// bats: fused binA + ts, role-dispatched (r20 form, unchanged).
// ---------------------------------------------------------------------------
__global__ __launch_bounds__(256, 4) void bats(
    const int* __restrict__ edges,
    int* __restrict__ gcur, uint2* __restrict__ ebin,
    int* __restrict__ ocnt, uint2* __restrict__ obuf,
    const float* __restrict__ nodes, const float* __restrict__ rels,
    const unsigned short* __restrict__ btn, const unsigned short* __restrict__ bts,
    unsigned char* __restrict__ T8, unsigned short* __restrict__ U,
    unsigned short* __restrict__ Spb)
{
    __shared__ __align__(16) char ldsRaw[6144 + EPB_A * 8];   // 38912 B
    int bid = blockIdx.x;
    int t   = threadIdx.x;

    if (bid < ABLK) {
        // ================= binA role =================
        int*   hist  = (int*)ldsRaw;                 // [512]
        int*   lpre  = (int*)(ldsRaw + 2048);        // [512]
        int*   base  = (int*)(ldsRaw + 4096);        // [512]
        uint2* stage = (uint2*)(ldsRaw + 6144);      // [4096]

        int eb = bid * EPB_A;
        hist[t] = 0; hist[t + 256] = 0;
        __syncthreads();

        int      bin_i[16];
        int      dst_i[16];
        unsigned pay_i[16];
        int      rnk_i[16];
        #pragma unroll
        for (int i = 0; i < 16; ++i) {
            int e = eb + i * 256 + t;
            bin_i[i] = -1;
            if (e < NEDGES) {
                int s = edges[3 * e], r = edges[3 * e + 1], d = edges[3 * e + 2];
                dst_i[i] = d;
                bin_i[i] = d >> 7;
                pay_i[i] = (unsigned)s | ((unsigned)r << 16);
                rnk_i[i] = atomicAdd(&hist[bin_i[i]], 1);
            }
        }
        __syncthreads();

        lpre[t] = hist[t]; lpre[t + 256] = hist[t + 256];
        __syncthreads();
        for (int d = 1; d < 512; d <<= 1) {
            int a0 = (t >= d) ? lpre[t - d] : 0;
            int a1 = lpre[t + 256 - d];
            __syncthreads();
            lpre[t] += a0; lpre[t + 256] += a1;
            __syncthreads();
        }

        if (t < NBIN && hist[t] > 0)
            base[t] = atomicAdd(gcur + (size_t)t * GSTR, hist[t]);
        if (t + 256 < NBIN && hist[t + 256] > 0)
            base[t + 256] = atomicAdd(gcur + (size_t)(t + 256) * GSTR, hist[t + 256]);
        __syncthreads();

        // stage: x = dst | min(q,0xFFFF)<<16 ; y = payload
        #pragma unroll
        for (int i = 0; i < 16; ++i) {
            if (bin_i[i] >= 0) {
                int b  = bin_i[i];
                int lp = (lpre[b] - hist[b]) + rnk_i[i];
                int q  = base[b] + rnk_i[i];
                unsigned qc = q < 0xFFFF ? (unsigned)q : 0xFFFFu;
                stage[lp] = make_uint2((unsigned)dst_i[i] | (qc << 16), pay_i[i]);
            }
        }
        __syncthreads();

        int ne = NEDGES - eb; if (ne > EPB_A) ne = EPB_A;
        for (int j = t; j < ne; j += 256) {
            uint2 rec = stage[j];
            unsigned dst = rec.x & 0xFFFFu;
            unsigned q   = rec.x >> 16;
            if (q < BINCAP)
                ebin[(size_t)(dst >> 7) * BINCAP + q] = make_uint2(dst, rec.y);
            else {
                int o = atomicAdd(ocnt, 1);
                if (o < OCAP) obuf[o] = make_uint2(dst, rec.y);
            }
        }
        return;
    }

    // ================= ts role =================
    unsigned short* ldsB = (unsigned short*)ldsRaw;
    float*          ldsS = (float*)ldsRaw;

    int blk = bid - ABLK;
    bool isRel = blk >= NODE_BLKS;
    const float* A = isRel ? rels : nodes;
    int nrows = isRel ? NRELS : NNODES;
    int rowbase = (isRel ? (blk - NODE_BLKS) : blk) * 64;

    int wv = t >> 6;
    int l  = t & 63;
    int r0 = rowbase + wv * 16;
    int m  = l & 15;
    int kg = l >> 4;
    int arow  = r0 + m;
    int arowc = arow < nrows ? arow : nrows - 1;

    s8f afrag[4];
    #pragma unroll
    for (int ks = 0; ks < 4; ++ks) {
        const float* p = A + (size_t)arowc * DIM + ks * 32 + kg * 8;
        float4 x = *(const float4*)p;
        float4 y = *(const float4*)(p + 4);
        s8f a;
        a[0] = (short)f2bf(x.x); a[1] = (short)f2bf(x.y);
        a[2] = (short)f2bf(x.z); a[3] = (short)f2bf(x.w);
        a[4] = (short)f2bf(y.x); a[5] = (short)f2bf(y.y);
        a[6] = (short)f2bf(y.z); a[7] = (short)f2bf(y.w);
        afrag[ks] = a;
    }

    // phase 1: A @ Wn -> f32 LDS tile -> fp8 T / bf16 U
    #pragma unroll
    for (int i = 0; i < 8; ++i) {
        int idx = t + i * 256;
        int col = idx >> 4, slot = idx & 15;
        *(uint4*)(ldsB + (size_t)col * BP + slot * 8) =
            *(const uint4*)(btn + (size_t)col * DIM + slot * 8);
    }
    __syncthreads();

    f4 acc[8];
    #pragma unroll
    for (int ct = 0; ct < 8; ++ct) {
        int col = ct * 16 + m;
        const unsigned short* bp = ldsB + (size_t)col * BP + kg * 8;
        f4 a = {0.f, 0.f, 0.f, 0.f};
        #pragma unroll
        for (int ks = 0; ks < 4; ++ks)
            a = __builtin_amdgcn_mfma_f32_16x16x32_bf16(afrag[ks], *(const s8f*)(bp + ks * 32), a, 0, 0, 0);
        acc[ct] = a;
    }
    __syncthreads();

    #pragma unroll
    for (int ct = 0; ct < 8; ++ct)
        #pragma unroll
        for (int r = 0; r < 4; ++r)
            ldsS[((size_t)wv * 16 + kg * 4 + r) * SP + ct * 16 + m] = acc[ct][r];
    __syncthreads();

    #pragma unroll
    for (int p = 0; p < 4; ++p) {
        int row = p * 4 + kg;
        int rg  = r0 + row;
        if (rg < nrows) {
            const float* rp = &ldsS[((size_t)wv * 16 + row) * SP + m * 8];
            float4 x = *(const float4*)rp;
            float4 y = *(const float4*)(rp + 4);
            if (!isRel) {
                uint2 o = { enc_fp8x4(x.x, x.y, x.z, x.w),
                            enc_fp8x4(y.x, y.y, y.z, y.w) };
                *(uint2*)(T8 + (size_t)rg * DIM + m * 8) = o;
            } else {
                uint4 o;
                o.x = (unsigned)f2bf(x.x) | ((unsigned)f2bf(x.y) << 16);
                o.y = (unsigned)f2bf(x.z) | ((unsigned)f2bf(x.w) << 16);
                o.z = (unsigned)f2bf(y.x) | ((unsigned)f2bf(y.y) << 16);
                o.w = (unsigned)f2bf(y.z) | ((unsigned)f2bf(y.w) << 16);
                *(uint4*)(U + (size_t)rg * DIM + m * 8) = o;
            }
        }
    }
    if (isRel) return;

    __syncthreads();

    // phase 2: Spb = bf16( A @ (I+Ws) )
    #pragma unroll
    for (int i = 0; i < 8; ++i) {
        int idx = t + i * 256;
        int col = idx >> 4, slot = idx & 15;
        *(uint4*)(ldsB + (size_t)col * BP + slot * 8) =
            *(const uint4*)(bts + (size_t)col * DIM + slot * 8);
    }
    __syncthreads();

    #pragma unroll
    for (int ct = 0; ct < 8; ++ct) {
        int col = ct * 16 + m;
        const unsigned short* bp = ldsB + (size_t)col * BP + kg * 8;
        f4 a = {0.f, 0.f, 0.f, 0.f};
        #pragma unroll
        for (int ks = 0; ks < 4; ++ks)
            a = __builtin_amdgcn_mfma_f32_16x16x32_bf16(afrag[ks], *(const s8f*)(bp + ks * 32), a, 0, 0, 0);
        acc[ct] = a;
    }
    __syncthreads();

    #pragma unroll
    for (int ct = 0; ct < 8; ++ct)
        #pragma unroll
        for (int r = 0; r < 4; ++r)
            ldsS[((size_t)wv * 16 + kg * 4 + r) * SP + ct * 16 + m] = acc[ct][r];
    __syncthreads();

    #pragma unroll
    for (int p = 0; p < 4; ++p) {
        int row = p * 4 + kg;
        int rg  = r0 + row;
        if (rg < NNODES) {
            unsigned short* orow = Spb + (size_t)rg * DIM;
            #pragma unroll
            for (int j = 0; j < 2; ++j) {
                int c0 = m * 4 + j * 64;
                float4 s = *(const float4*)&ldsS[((size_t)wv * 16 + row) * SP + c0];
                uint2 o = { (unsigned)f2bf(s.x) | ((unsigned)f2bf(s.y) << 16),
                            (unsigned)f2bf(s.z) | ((unsigned)f2bf(s.w) << 16) };
                *(uint2*)(orow + c0) = o;
            }
        }
    }
}

// ---------------------------------------------------------------------------
// gatherbin: HALF-BIN blocks. 782 x 256-thread blocks; block (bin, hb) scans
// the parent bin's ebin segment and stages only its 64 dsts in LDS
// (24.8KB -> 6 blocks/CU, tail ~9%). Each half-wave owns 8 nodes.
// ---------------------------------------------------------------------------
#define ACCE(e) { \
    unsigned tw = *(const unsigned*)(T8 + (size_t)((e) & 0xFFFFu) * DIM + c * 4); \
    uint2 uu = *(const uint2*)(U + (size_t)((e) >> 16) * DIM + c * 4); \
    float tf[4]; dec_fp8x4(tw, tf); \
    acc.x += tf[0] + bflo(uu.x); acc.y += tf[1] + bfhi(uu.x); \
    acc.z += tf[2] + bflo(uu.y); acc.w += tf[3] + bfhi(uu.y); }

__global__ __launch_bounds__(256) void gatherbin(
    const unsigned char* __restrict__ T8, const unsigned short* __restrict__ U,
    const int* __restrict__ gcur, const uint2* __restrict__ ebin,
    const int* __restrict__ ocnt, const uint2* __restrict__ obuf,
    const unsigned short* __restrict__ Spb,
    const float* __restrict__ nodes, const float* __restrict__ wse,
    float* __restrict__ outp)
{
    __shared__ unsigned list[64 * LCAP];   // 24 KB
    __shared__ int      cnt[64];

    int bin = blockIdx.x >> 1;
    int hb  = blockIdx.x & 1;
    int t   = threadIdx.x;
    int totraw = gcur[(size_t)bin * GSTR];
    int total  = totraw < BINCAP ? totraw : BINCAP;

    if (t < 64) cnt[t] = 0;
    __syncthreads();

    for (int j = t; j < total; j += 256) {
        uint2 rec = ebin[(size_t)bin * BINCAP + j];
        int dloc = (int)(rec.x & (DPB - 1));
        if ((dloc >> 6) == hb) {
            int dl = dloc & 63;
            int rk = atomicAdd(&cnt[dl], 1);
            if (rk < LCAP) list[dl * LCAP + rk] = rec.y;
        }
    }
    __syncthreads();

    int wv = t >> 6;        // 0..3
    int l  = t & 63;
    int half = l >> 5;
    int c  = l & 31;

    int oc = *ocnt;
    if (oc > OCAP) oc = OCAP;

    #pragma unroll
    for (int r = 0; r < 8; ++r) {
        int dl = r * 8 + wv * 2 + half;
        int n  = bin * DPB + hb * 64 + dl;
        if (n >= NNODES) continue;
        int degb = cnt[dl];
        uint2 sp = *(const uint2*)(Spb + (size_t)n * DIM + c * 4);  // hoisted
        float4 acc = make_float4(0.f, 0.f, 0.f, 0.f);

        if (degb <= LCAP) {
            const unsigned* lp = &list[dl * LCAP];
            int j = 0;
            for (; j + 3 < degb; j += 4) {
                unsigned e0 = lp[j], e1 = lp[j + 1];
                unsigned e2 = lp[j + 2], e3 = lp[j + 3];
                ACCE(e0); ACCE(e1); ACCE(e2); ACCE(e3);
            }
            for (; j < degb; ++j) { unsigned e0 = lp[j]; ACCE(e0); }
        } else {
            // ~impossible (P[deg>96] ~ 1e-50) but exact: rescan the bin
            for (int j = 0; j < total; ++j) {
                uint2 rec = ebin[(size_t)bin * BINCAP + j];
                if ((int)(rec.x & (DPB - 1)) == hb * 64 + dl) {
                    unsigned e0 = rec.y; ACCE(e0);
                }
            }
        }

        int dt = 0;
        for (int k = 0; k < oc; ++k) {          // oc ~ 0
            uint2 e2 = obuf[k];
            if ((int)e2.x == n) { dt++; unsigned e0 = e2.y; ACCE(e0); }
        }
        int deg = degb + dt;

        if (deg > 0) {
            float inv = 1.0f / (float)deg;
            float4 o = { bflo(sp.x) + acc.x * inv, bfhi(sp.x) + acc.y * inv,
                         bflo(sp.y) + acc.z * inv, bfhi(sp.y) + acc.w * inv };
            *(float4*)(outp + (size_t)n * DIM + c * 4) = o;
        } else {
            // rare (~6e-6 per node): out = h + h @ Wse
            float s0 = 0, s1 = 0, s2 = 0, s3 = 0;
            for (int k = 0; k < DIM; ++k) {
                float hk = nodes[(size_t)n * DIM + k];
                const float* wr = wse + (size_t)k * DIM + c * 4;
                s0 += hk * wr[0]; s1 += hk * wr[1];
                s2 += hk * wr[2]; s3 += hk * wr[3];
            }
            float4 hv = *(const float4*)(nodes + (size_t)n * DIM + c * 4);
            float4 o = { hv.x + s0, hv.y + s1, hv.z + s2, hv.w + s3 };
            *(float4*)(outp + (size_t)n * DIM + c * 4) = o;
        }
    }
}

// ---------------------------------------------------------------------------
extern "C" void kernel_launch(void* const* d_in, const int* in_sizes, int n_in,
                              void* d_out, int out_size, void* d_ws, size_t ws_size,
                              hipStream_t stream)
{
    const float* nodes = (const float*)d_in[0];
    const float* rels  = (const float*)d_in[1];
    const int*   edges = (const int*)d_in[2];
    const float* wn    = (const float*)d_in[3];
    const float* wsf   = (const float*)d_in[4];
    const float* wse   = (const float*)d_in[5];
    float* out = (float*)d_out;

    char* ws = (char*)d_ws;
    int*            gcur  = (int*)(ws + OFF_GCUR_B);
    int*            ocnt  = (int*)(ws + OFF_OCNT_B);
    uint2*          obuf  = (uint2*)(ws + OFF_OBUF_B);
    uint2*          ebin  = (uint2*)(ws + OFF_EBIN_B);
    unsigned short* btn   = (unsigned short*)(ws + OFF_BTN_B);
    unsigned short* bts   = (unsigned short*)(ws + OFF_BTS_B);
    unsigned char*  T8    = (unsigned char*)(ws + OFF_T_B);
    unsigned short* U     = (unsigned short*)(ws + OFF_U_B);
    unsigned short* Spb   = (unsigned short*)(ws + OFF_SPB_B);

    prep<<<PREP_BLKS, 256, 0, stream>>>(wn, wsf, btn, bts, (int4*)gcur);

    bats<<<BATS_BLKS, 256, 0, stream>>>(edges, gcur, ebin, ocnt, obuf,
                                        nodes, rels, btn, bts, T8, U, Spb);

    gatherbin<<<GB_BLKS, 256, 0, stream>>>(T8, U, gcur, ebin, ocnt, obuf, Spb,
                                           nodes, wse, out);
}

// Round 23
// 61.819 us; speedup vs baseline: 1.5356x; 1.0000x over previous
//
#include <hip/hip_runtime.h>

// URGCN layer, MI355X — round 23 (revert of r22's failed cooperative launch).
// r22 post-mortem: hipLaunchCooperativeKernel silently failed (unchecked
// error; kernel never ran). Reverting to the r21 known-good 3-dispatch
// pipeline (61.8us). Gather is at the random-short-read memory-system floor;
// binA hides under ts; remaining ~6us is launch-boundary overhead whose only
// remaining fix (cooperative fusion) is unsafe under this harness.
//
// Algebra: msg_agg = (Σ_e T[src] + u[rel]) / deg, T = h@Wn (fp8 store),
//          u = rel@Wn (bf16).  out = Spb + msg_agg, Spb = h@(I+Wself) (bf16).

constexpr int NNODES = 50000;
constexpr int NEDGES = 600000;
constexpr int NRELS  = 500;
constexpr int DIM    = 128;

constexpr int DPB    = 128;                        // dsts per bin
constexpr int NBIN   = (NNODES + DPB - 1) / DPB;   // 391
constexpr int BINCAP = 2048;                       // edges per bin (13 sigma)
constexpr int EPB_A  = 4096;                       // edges per binA block
constexpr int ABLK   = (NEDGES + EPB_A - 1) / EPB_A; // 147
constexpr int GSTR   = 16;                         // gcur stride (ints, 64B)
constexpr int OCAP   = 8192;
constexpr int LCAP   = 96;                         // LDS list cap per node

constexpr int NODE_BLKS = (NNODES + 63) / 64;   // 782
constexpr int REL_BLKS  = (NRELS  + 63) / 64;   // 8
constexpr int TS_BLKS   = NODE_BLKS + REL_BLKS; // 790
constexpr int BATS_BLKS = ABLK + TS_BLKS;       // 937 (binA role first)

constexpr int BP = 136;   // LDS B row pitch (shorts)
constexpr int SP = 132;   // LDS f32 tile pitch (floats)

constexpr int WCONV_BLKS = (DIM * DIM + 255) / 256;   // 64
constexpr int ZERO_INT4S = 1604;                      // gcur + ocnt region
constexpr int ZERO_BLKS  = (ZERO_INT4S + 255) / 256;  // 7
constexpr int PREP_BLKS  = WCONV_BLKS + ZERO_BLKS;    // 71

constexpr int GB_BLKS = NBIN * 2;                     // 782 half-bin blocks

// ---------------- workspace layout (bytes) ----------------
constexpr size_t OFF_GCUR_B = 0;          // int[NBIN*16] padded cursors
constexpr size_t OFF_OCNT_B = 25600;      // int
constexpr size_t OFF_OBUF_B = 25664;      // uint2[8192]
constexpr size_t OFF_EBIN_B = 91200;      // uint2[NBIN*BINCAP] 6.4MB
constexpr size_t OFF_BTN_B  = 6497344;    // ushort[128*128] Wn^T bf16
constexpr size_t OFF_BTS_B  = 6530112;    // ushort[128*128] (I+Ws)^T bf16
constexpr size_t OFF_T_B    = 6562880;    // uchar[50000*128] fp8 T (6.4MB)
constexpr size_t OFF_U_B    = 12962880;   // ushort[500*128] bf16 U
constexpr size_t OFF_SPB_B  = 13090880;   // ushort[50000*128] bf16 Sp (12.8MB)

typedef short s8f __attribute__((ext_vector_type(8)));   // 8 bf16
typedef float f4  __attribute__((ext_vector_type(4)));   // MFMA acc

static __device__ __forceinline__ unsigned short f2bf(float f) {
    unsigned u = __builtin_bit_cast(unsigned, f);
    u += 0x7FFFu + ((u >> 16) & 1u);
    return (unsigned short)(u >> 16);
}
static __device__ __forceinline__ float bflo(unsigned v) {
    return __builtin_bit_cast(float, v << 16);
}
static __device__ __forceinline__ float bfhi(unsigned v) {
    return __builtin_bit_cast(float, v & 0xFFFF0000u);
}

// ---- fp8 e4m3 pack/unpack (HW converts when available) ----
static __device__ __forceinline__ void dec_fp8x4(unsigned w, float* f) {
#if __has_builtin(__builtin_amdgcn_cvt_pk_f32_fp8)
    typedef float f2v __attribute__((ext_vector_type(2)));
    f2v lo = __builtin_amdgcn_cvt_pk_f32_fp8((int)w, false);
    f2v hi = __builtin_amdgcn_cvt_pk_f32_fp8((int)w, true);
    f[0] = lo[0]; f[1] = lo[1]; f[2] = hi[0]; f[3] = hi[1];
#else
    #pragma unroll
    for (int i = 0; i < 4; ++i) {
        unsigned b = (w >> (8 * i)) & 0xFFu;
        unsigned e = (b >> 3) & 15u, m = b & 7u;
        float v = e ? __builtin_bit_cast(float, ((e + 120u) << 23) | (m << 20))
                    : (float)m * 0.001953125f;
        f[i] = (b & 0x80u) ? -v : v;
    }
#endif
}
static __device__ __forceinline__ unsigned enc_fp8x4(float a, float b,
                                                     float cc, float d) {
#if __has_builtin(__builtin_amdgcn_cvt_pk_fp8_f32)
    int w = __builtin_amdgcn_cvt_pk_fp8_f32(a, b, 0, false);
    w = __builtin_amdgcn_cvt_pk_fp8_f32(cc, d, w, true);
    return (unsigned)w;
#else
    float vv[4] = {a, b, cc, d};
    unsigned w = 0;
    #pragma unroll
    for (int i = 0; i < 4; ++i) {
        unsigned u = __builtin_bit_cast(unsigned, vv[i]);
        unsigned s = u >> 31;
        unsigned au = u & 0x7FFFFFFFu;
        float af = __builtin_bit_cast(float, au);
        unsigned byte;
        if (af < 0.015625f) byte = s << 7;
        else {
            if (af > 448.f) au = 0x43E00000u;
            unsigned lsb = (au >> 20) & 1u;
            au += 0x7FFFFu + lsb;
            int e8 = (int)(au >> 23) - 120;
            unsigned m3 = (au >> 20) & 7u;
            if (e8 > 15) { e8 = 15; m3 = 6; }
            byte = (s << 7) | ((unsigned)e8 << 3) | m3;
        }
        w |= byte << (8 * i);
    }
    return w;
#endif
}

// ---------------------------------------------------------------------------
// prep: blocks [0,64) convert weights; blocks [64,71) zero gcur+ocnt.
__global__ __launch_bounds__(256) void prep(const float* __restrict__ wn,
                                            const float* __restrict__ wsf,
                                            unsigned short* __restrict__ btn,
                                            unsigned short* __restrict__ bts,
                                            int4* __restrict__ z4)
{
    int b = blockIdx.x;
    if (b < WCONV_BLKS) {
        int idx = b * 256 + threadIdx.x;
        int k = idx >> 7, j = idx & 127;
        btn[(size_t)j * DIM + k] = f2bf(wn[idx]);                         // Wn^T
        bts[(size_t)j * DIM + k] = f2bf(wsf[idx] + (k == j ? 1.f : 0.f)); // (I+Ws)^T
    } else {
        int idx = (b - WCONV_BLKS) * 256 + threadIdx.x;
        if (idx < ZERO_INT4S) z4[idx] = make_int4(0, 0, 0, 0);
    }
}

// ---------------------------------------------------------------------------
// bats: fused binA + ts, role-dispatched (r20 form, unchanged).
// ---------------------------------------------------------------------------
__global__ __launch_bounds__(256, 4) void bats(
    const int* __restrict__ edges,
    int* __restrict__ gcur, uint2* __restrict__ ebin,
    int* __restrict__ ocnt, uint2* __restrict__ obuf,
    const float* __restrict__ nodes, const float* __restrict__ rels,
    const unsigned short* __restrict__ btn, const unsigned short* __restrict__ bts,
    unsigned char* __restrict__ T8, unsigned short* __restrict__ U,
    unsigned short* __restrict__ Spb)
{
    __shared__ __align__(16) char ldsRaw[6144 + EPB_A * 8];   // 38912 B
    int bid = blockIdx.x;
    int t   = threadIdx.x;

    if (bid < ABLK) {
        // ================= binA role =================
        int*   hist  = (int*)ldsRaw;                 // [512]
        int*   lpre  = (int*)(ldsRaw + 2048);        // [512]
        int*   base  = (int*)(ldsRaw + 4096);        // [512]
        uint2* stage = (uint2*)(ldsRaw + 6144);      // [4096]

        int eb = bid * EPB_A;
        hist[t] = 0; hist[t + 256] = 0;
        __syncthreads();

        int      bin_i[16];
        int      dst_i[16];
        unsigned pay_i[16];
        int      rnk_i[16];
        #pragma unroll
        for (int i = 0; i < 16; ++i) {
            int e = eb + i * 256 + t;
            bin_i[i] = -1;
            if (e < NEDGES) {
                int s = edges[3 * e], r = edges[3 * e + 1], d = edges[3 * e + 2];
                dst_i[i] = d;
                bin_i[i] = d >> 7;
                pay_i[i] = (unsigned)s | ((unsigned)r << 16);
                rnk_i[i] = atomicAdd(&hist[bin_i[i]], 1);
            }
        }
        __syncthreads();

        lpre[t] = hist[t]; lpre[t + 256] = hist[t + 256];
        __syncthreads();
        for (int d = 1; d < 512; d <<= 1) {
            int a0 = (t >= d) ? lpre[t - d] : 0;
            int a1 = lpre[t + 256 - d];
            __syncthreads();
            lpre[t] += a0; lpre[t + 256] += a1;
            __syncthreads();
        }

        if (t < NBIN && hist[t] > 0)
            base[t] = atomicAdd(gcur + (size_t)t * GSTR, hist[t]);
        if (t + 256 < NBIN && hist[t + 256] > 0)
            base[t + 256] = atomicAdd(gcur + (size_t)(t + 256) * GSTR, hist[t + 256]);
        __syncthreads();

        // stage: x = dst | min(q,0xFFFF)<<16 ; y = payload
        #pragma unroll
        for (int i = 0; i < 16; ++i) {
            if (bin_i[i] >= 0) {
                int b  = bin_i[i];
                int lp = (lpre[b] - hist[b]) + rnk_i[i];
                int q  = base[b] + rnk_i[i];
                unsigned qc = q < 0xFFFF ? (unsigned)q : 0xFFFFu;
                stage[lp] = make_uint2((unsigned)dst_i[i] | (qc << 16), pay_i[i]);
            }
        }
        __syncthreads();

        int ne = NEDGES - eb; if (ne > EPB_A) ne = EPB_A;
        for (int j = t; j < ne; j += 256) {
            uint2 rec = stage[j];
            unsigned dst = rec.x & 0xFFFFu;
            unsigned q   = rec.x >> 16;
            if (q < BINCAP)
                ebin[(size_t)(dst >> 7) * BINCAP + q] = make_uint2(dst, rec.y);
            else {
                int o = atomicAdd(ocnt, 1);
                if (o < OCAP) obuf[o] = make_uint2(dst, rec.y);
            }
        }
        return;
    }

    // ================= ts role =================
    unsigned short* ldsB = (unsigned short*)ldsRaw;
    float*          ldsS = (float*)ldsRaw;

    int blk = bid - ABLK;
    bool isRel = blk >= NODE_BLKS;
    const float* A = isRel ? rels : nodes;
    int nrows = isRel ? NRELS : NNODES;
    int rowbase = (isRel ? (blk - NODE_BLKS) : blk) * 64;

    int wv = t >> 6;
    int l  = t & 63;
    int r0 = rowbase + wv * 16;
    int m  = l & 15;
    int kg = l >> 4;
    int arow  = r0 + m;
    int arowc = arow < nrows ? arow : nrows - 1;

    s8f afrag[4];
    #pragma unroll
    for (int ks = 0; ks < 4; ++ks) {
        const float* p = A + (size_t)arowc * DIM + ks * 32 + kg * 8;
        float4 x = *(const float4*)p;
        float4 y = *(const float4*)(p + 4);
        s8f a;
        a[0] = (short)f2bf(x.x); a[1] = (short)f2bf(x.y);
        a[2] = (short)f2bf(x.z); a[3] = (short)f2bf(x.w);
        a[4] = (short)f2bf(y.x); a[5] = (short)f2bf(y.y);
        a[6] = (short)f2bf(y.z); a[7] = (short)f2bf(y.w);
        afrag[ks] = a;
    }

    // phase 1: A @ Wn -> f32 LDS tile -> fp8 T / bf16 U
    #pragma unroll
    for (int i = 0; i < 8; ++i) {
        int idx = t + i * 256;
        int col = idx >> 4, slot = idx & 15;
        *(uint4*)(ldsB + (size_t)col * BP + slot * 8) =
            *(const uint4*)(btn + (size_t)col * DIM + slot * 8);
    }
    __syncthreads();

    f4 acc[8];
    #pragma unroll
    for (int ct = 0; ct < 8; ++ct) {
        int col = ct * 16 + m;
        const unsigned short* bp = ldsB + (size_t)col * BP + kg * 8;
        f4 a = {0.f, 0.f, 0.f, 0.f};
        #pragma unroll
        for (int ks = 0; ks < 4; ++ks)
            a = __builtin_amdgcn_mfma_f32_16x16x32_bf16(afrag[ks], *(const s8f*)(bp + ks * 32), a, 0, 0, 0);
        acc[ct] = a;
    }
    __syncthreads();

    #pragma unroll
    for (int ct = 0; ct < 8; ++ct)
        #pragma unroll
        for (int r = 0; r < 4; ++r)
            ldsS[((size_t)wv * 16 + kg * 4 + r) * SP + ct * 16 + m] = acc[ct][r];
    __syncthreads();

    #pragma unroll
    for (int p = 0; p < 4; ++p) {
        int row = p * 4 + kg;
        int rg  = r0 + row;
        if (rg < nrows) {
            const float* rp = &ldsS[((size_t)wv * 16 + row) * SP + m * 8];
            float4 x = *(const float4*)rp;
            float4 y = *(const float4*)(rp + 4);
            if (!isRel) {
                uint2 o = { enc_fp8x4(x.x, x.y, x.z, x.w),
                            enc_fp8x4(y.x, y.y, y.z, y.w) };
                *(uint2*)(T8 + (size_t)rg * DIM + m * 8) = o;
            } else {
                uint4 o;
                o.x = (unsigned)f2bf(x.x) | ((unsigned)f2bf(x.y) << 16);
                o.y = (unsigned)f2bf(x.z) | ((unsigned)f2bf(x.w) << 16);
                o.z = (unsigned)f2bf(y.x) | ((unsigned)f2bf(y.y) << 16);
                o.w = (unsigned)f2bf(y.z) | ((unsigned)f2bf(y.w) << 16);
                *(uint4*)(U + (size_t)rg * DIM + m * 8) = o;
            }
        }
    }
    if (isRel) return;

    __syncthreads();

    // phase 2: Spb = bf16( A @ (I+Ws) )
    #pragma unroll
    for (int i = 0; i < 8; ++i) {
        int idx = t + i * 256;
        int col = idx >> 4, slot = idx & 15;
        *(uint4*)(ldsB + (size_t)col * BP + slot * 8) =
            *(const uint4*)(bts + (size_t)col * DIM + slot * 8);
    }
    __syncthreads();

    #pragma unroll
    for (int ct = 0; ct < 8; ++ct) {
        int col = ct * 16 + m;
        const unsigned short* bp = ldsB + (size_t)col * BP + kg * 8;
        f4 a = {0.f, 0.f, 0.f, 0.f};
        #pragma unroll
        for (int ks = 0; ks < 4; ++ks)
            a = __builtin_amdgcn_mfma_f32_16x16x32_bf16(afrag[ks], *(const s8f*)(bp + ks * 32), a, 0, 0, 0);
        acc[ct] = a;
    }
    __syncthreads();

    #pragma unroll
    for (int ct = 0; ct < 8; ++ct)
        #pragma unroll
        for (int r = 0; r < 4; ++r)
            ldsS[((size_t)wv * 16 + kg * 4 + r) * SP + ct * 16 + m] = acc[ct][r];
    __syncthreads();

    #pragma unroll
    for (int p = 0; p < 4; ++p) {
        int row = p * 4 + kg;
        int rg  = r0 + row;
        if (rg < NNODES) {
            unsigned short* orow = Spb + (size_t)rg * DIM;
            #pragma unroll
            for (int j = 0; j < 2; ++j) {
                int c0 = m * 4 + j * 64;
                float4 s = *(const float4*)&ldsS[((size_t)wv * 16 + row) * SP + c0];
                uint2 o = { (unsigned)f2bf(s.x) | ((unsigned)f2bf(s.y) << 16),
                            (unsigned)f2bf(s.z) | ((unsigned)f2bf(s.w) << 16) };
                *(uint2*)(orow + c0) = o;
            }
        }
    }
}

// ---------------------------------------------------------------------------
// gatherbin: HALF-BIN blocks. 782 x 256-thread blocks; block (bin, hb) scans
// the parent bin's ebin segment and stages only its 64 dsts in LDS
// (24.8KB -> 6 blocks/CU). Each half-wave owns 8 nodes.
// ---------------------------------------------------------------------------
#define ACCE(e) { \
    unsigned tw = *(const unsigned*)(T8 + (size_t)((e) & 0xFFFFu) * DIM + c * 4); \
    uint2 uu = *(const uint2*)(U + (size_t)((e) >> 16) * DIM + c * 4); \
    float tf[4]; dec_fp8x4(tw, tf); \
    acc.x += tf[0] + bflo(uu.x); acc.y += tf[1] + bfhi(uu.x); \
    acc.z += tf[2] + bflo(uu.y); acc.w += tf[3] + bfhi(uu.y); }

__global__ __launch_bounds__(256) void gatherbin(
    const unsigned char* __restrict__ T8, const unsigned short* __restrict__ U,
    const int* __restrict__ gcur, const uint2* __restrict__ ebin,
    const int* __restrict__ ocnt, const uint2* __restrict__ obuf,
    const unsigned short* __restrict__ Spb,
    const float* __restrict__ nodes, const float* __restrict__ wse,
    float* __restrict__ outp)
{
    __shared__ unsigned list[64 * LCAP];   // 24 KB
    __shared__ int      cnt[64];

    int bin = blockIdx.x >> 1;
    int hb  = blockIdx.x & 1;
    int t   = threadIdx.x;
    int totraw = gcur[(size_t)bin * GSTR];
    int total  = totraw < BINCAP ? totraw : BINCAP;

    if (t < 64) cnt[t] = 0;
    __syncthreads();

    for (int j = t; j < total; j += 256) {
        uint2 rec = ebin[(size_t)bin * BINCAP + j];
        int dloc = (int)(rec.x & (DPB - 1));
        if ((dloc >> 6) == hb) {
            int dl = dloc & 63;
            int rk = atomicAdd(&cnt[dl], 1);
            if (rk < LCAP) list[dl * LCAP + rk] = rec.y;
        }
    }
    __syncthreads();

    int wv = t >> 6;        // 0..3
    int l  = t & 63;
    int half = l >> 5;
    int c  = l & 31;

    int oc = *ocnt;
    if (oc > OCAP) oc = OCAP;

    #pragma unroll
    for (int r = 0; r < 8; ++r) {
        int dl = r * 8 + wv * 2 + half;
        int n  = bin * DPB + hb * 64 + dl;
        if (n >= NNODES) continue;
        int degb = cnt[dl];
        uint2 sp = *(const uint2*)(Spb + (size_t)n * DIM + c * 4);  // hoisted
        float4 acc = make_float4(0.f, 0.f, 0.f, 0.f);

        if (degb <= LCAP) {
            const unsigned* lp = &list[dl * LCAP];
            int j = 0;
            for (; j + 3 < degb; j += 4) {
                unsigned e0 = lp[j], e1 = lp[j + 1];
                unsigned e2 = lp[j + 2], e3 = lp[j + 3];
                ACCE(e0); ACCE(e1); ACCE(e2); ACCE(e3);
            }
            for (; j < degb; ++j) { unsigned e0 = lp[j]; ACCE(e0); }
        } else {
            // ~impossible (P[deg>96] ~ 1e-50) but exact: rescan the bin
            for (int j = 0; j < total; ++j) {
                uint2 rec = ebin[(size_t)bin * BINCAP + j];
                if ((int)(rec.x & (DPB - 1)) == hb * 64 + dl) {
                    unsigned e0 = rec.y; ACCE(e0);
                }
            }
        }

        int dt = 0;
        for (int k = 0; k < oc; ++k) {          // oc ~ 0
            uint2 e2 = obuf[k];
            if ((int)e2.x == n) { dt++; unsigned e0 = e2.y; ACCE(e0); }
        }
        int deg = degb + dt;

        if (deg > 0) {
            float inv = 1.0f / (float)deg;
            float4 o = { bflo(sp.x) + acc.x * inv, bfhi(sp.x) + acc.y * inv,
                         bflo(sp.y) + acc.z * inv, bfhi(sp.y) + acc.w * inv };
            *(float4*)(outp + (size_t)n * DIM + c * 4) = o;
        } else {
            // rare (~6e-6 per node): out = h + h @ Wse
            float s0 = 0, s1 = 0, s2 = 0, s3 = 0;
            for (int k = 0; k < DIM; ++k) {
                float hk = nodes[(size_t)n * DIM + k];
                const float* wr = wse + (size_t)k * DIM + c * 4;
                s0 += hk * wr[0]; s1 += hk * wr[1];
                s2 += hk * wr[2]; s3 += hk * wr[3];
            }
            float4 hv = *(const float4*)(nodes + (size_t)n * DIM + c * 4);
            float4 o = { hv.x + s0, hv.y + s1, hv.z + s2, hv.w + s3 };
            *(float4*)(outp + (size_t)n * DIM + c * 4) = o;
        }
    }
}

// ---------------------------------------------------------------------------
extern "C" void kernel_launch(void* const* d_in, const int* in_sizes, int n_in,
                              void* d_out, int out_size, void* d_ws, size_t ws_size,
                              hipStream_t stream)
{
    const float* nodes = (const float*)d_in[0];
    const float* rels  = (const float*)d_in[1];
    const int*   edges = (const int*)d_in[2];
    const float* wn    = (const float*)d_in[3];
    const float* wsf   = (const float*)d_in[4];
    const float* wse   = (const float*)d_in[5];
    float* out = (float*)d_out;

    char* ws = (char*)d_ws;
    int*            gcur  = (int*)(ws + OFF_GCUR_B);
    int*            ocnt  = (int*)(ws + OFF_OCNT_B);
    uint2*          obuf  = (uint2*)(ws + OFF_OBUF_B);
    uint2*          ebin  = (uint2*)(ws + OFF_EBIN_B);
    unsigned short* btn   = (unsigned short*)(ws + OFF_BTN_B);
    unsigned short* bts   = (unsigned short*)(ws + OFF_BTS_B);
    unsigned char*  T8    = (unsigned char*)(ws + OFF_T_B);
    unsigned short* U     = (unsigned short*)(ws + OFF_U_B);
    unsigned short* Spb   = (unsigned short*)(ws + OFF_SPB_B);

    prep<<<PREP_BLKS, 256, 0, stream>>>(wn, wsf, btn, bts, (int4*)gcur);

    bats<<<BATS_BLKS, 256, 0, stream>>>(edges, gcur, ebin, ocnt, obuf,
                                        nodes, rels, btn, bts, T8, U, Spb);

    gatherbin<<<GB_BLKS, 256, 0, stream>>>(T8, U, gcur, ebin, ocnt, obuf, Spb,
                                           nodes, wse, out);
}